// Round 6
// baseline (212.968 us; speedup 1.0000x reference)
//
#include <hip/hip_runtime.h>
#include <math.h>

#define N_N 20000
#define N_E 160000
#define PSW 1088   // Ps row stride in cols (136 chunks of 8; 132 used + pad)

typedef __attribute__((ext_vector_type(8))) short bfrag;
typedef __attribute__((ext_vector_type(4))) float facc;

__device__ __forceinline__ unsigned short f2bf(float f) {
  union { float f; unsigned u; } v; v.f = f;
  unsigned u = v.u;
  return (unsigned short)((u + 0x7FFF + ((u >> 16) & 1)) >> 16);
}
__device__ __forceinline__ unsigned pk2(float a, float b) {
  return (unsigned)f2bf(a) | ((unsigned)f2bf(b) << 16);
}
__device__ __forceinline__ float bflo(unsigned u) {
  union { unsigned u; float f; } v; v.u = u << 16; return v.f;
}
__device__ __forceinline__ float bfhi(unsigned u) {
  union { unsigned u; float f; } v; v.u = u & 0xffff0000u; return v.f;
}

// ---------------- edge MLP layer 1 -> bf16 he, written PERMUTED to dst-sorted order ------
__global__ __launch_bounds__(256) void k_mlp1(const float* __restrict__ ea,
    const float* __restrict__ w1, const float* __restrict__ b1,
    const int* __restrict__ perm, unsigned short* __restrict__ hes) {
  int t = threadIdx.x, w = t >> 6, j = t & 63;
  int e0 = (blockIdx.x * 4 + w) * 8;
  float wr[16];
#pragma unroll
  for (int i = 0; i < 16; ++i) wr[i] = w1[j * 16 + i];
  float bj = b1[j];
#pragma unroll
  for (int q = 0; q < 8; ++q) {
    int e = e0 + q;
    const float* a = ea + (size_t)e * 16;
    float s = bj;
#pragma unroll
    for (int i = 0; i < 16; ++i) s += a[i] * wr[i];
    hes[(size_t)perm[e] * 64 + j] = f2bf(fmaxf(s, 0.f));
  }
}

// ---------------- CSR build by dst ----------------
__global__ __launch_bounds__(256) void k_hist(const int* __restrict__ eidx,
    int* __restrict__ cnt) {
  int e = blockIdx.x * 256 + threadIdx.x;
  atomicAdd(&cnt[eidx[N_E + e]], 1);
}

__global__ __launch_bounds__(1024) void k_scan(int* __restrict__ hist,
    int* __restrict__ starts) {
  __shared__ int part[1024];
  int t = threadIdx.x;
  const int CH = 20;
  int lo = t * CH;
  int hi = lo + CH; if (hi > N_N) hi = N_N;
  int s = 0;
  for (int i = lo; i < hi; ++i) s += hist[i];
  part[t] = s;
  __syncthreads();
  for (int off = 1; off < 1024; off <<= 1) {
    int v = (t >= off) ? part[t - off] : 0;
    __syncthreads();
    part[t] += v;
    __syncthreads();
  }
  int run = (t == 0) ? 0 : part[t - 1];
  for (int i = lo; i < hi; ++i) {
    int h = hist[i];
    starts[i] = run;
    hist[i] = run;          // cursor seed
    run += h;
  }
  if (t == 1023) starts[N_N] = part[1023];
}

__global__ __launch_bounds__(256) void k_scatter(const int* __restrict__ eidx,
    int* __restrict__ cur, int* __restrict__ perm, int* __restrict__ srcl) {
  int e = blockIdx.x * 256 + threadIdx.x;
  int dn = eidx[N_E + e];
  int pos = atomicAdd(&cur[dn], 1);
  perm[e] = pos;
  srcl[pos] = eidx[e];
}

// ---------------- pack B (split-K order), B2 (qkv) fragment layouts ----------------
// kb 0..31: orig rows d*64+k, k in [0,32), d=kb.  kb=32: xsum rows (2048..2079).
// kb 33..64: orig rows d*64+32+k', d=kb-33.       kb=65: xcnt rows (2080..2111).
__global__ __launch_bounds__(256) void k_pack(const float* __restrict__ w2,
    const float* __restrict__ b2f, const float* __restrict__ rootw,
    const float* __restrict__ inw,
    unsigned short* __restrict__ Bp, unsigned short* __restrict__ B2p) {
  int idx = blockIdx.x * 256 + threadIdx.x;
  if (idx < 135168) {
    int i = idx & 7, l = (idx >> 3) & 63, cbkb = idx >> 9;
    int cb = cbkb & 3, kb = cbkb >> 2;
    int rr = ((l >> 4) << 3) + i;
    int c = (cb << 4) + (l & 15);
    int r;
    if (kb < 32) r = kb * 64 + rr;
    else if (kb == 32) r = 2048 + rr;
    else if (kb < 65) r = (kb - 33) * 64 + 32 + rr;
    else r = 2080 + rr;
    float v;
    if (r < 2048) { int d = r >> 6, k = r & 63; v = w2[((d << 6) + c) * 64 + k]; }
    else if (r < 2080) v = b2f[((r - 2048) << 6) + c];
    else v = rootw[((r - 2080) << 6) + c];
    Bp[idx] = f2bf(v);
  } else if (idx < 135168 + 12288) {
    int k2 = idx - 135168;
    int i = k2 & 7, l = (k2 >> 3) & 63, cbkb = k2 >> 9;
    int cb = cbkb % 12, kb = cbkb / 12;
    int r = kb * 32 + ((l >> 4) << 3) + i;
    int c = (cb << 4) + (l & 15);
    B2p[k2] = f2bf(inw[c * 64 + r]);
  }
}

// ---------------- FUSED: split-K P-build (LDS) + MFMA GEMM + mean/bias/relu + QKV --------
// Block = 16 nodes. Per half: Ps[16][1056(+pad)] bf16, chunk c of row m at chunk c^(m&7).
// Lane l: d1=l>>2, d2=d1+16, kc=l&3 -> owns chunks {l, l+64}; k-range kc*8..+8 (per half).
#define FMA8(hv, base, xv) \
  acc[base + 0] += xv * bflo(hv.x); acc[base + 1] += xv * bfhi(hv.x); \
  acc[base + 2] += xv * bflo(hv.y); acc[base + 3] += xv * bfhi(hv.y); \
  acc[base + 4] += xv * bflo(hv.z); acc[base + 5] += xv * bfhi(hv.z); \
  acc[base + 6] += xv * bflo(hv.w); acc[base + 7] += xv * bfhi(hv.w);

__global__ __launch_bounds__(256, 4) void k_fused(const float* __restrict__ x,
    const unsigned short* __restrict__ hes, const int* __restrict__ starts,
    const int* __restrict__ srcl,
    const unsigned short* __restrict__ Bp, const unsigned short* __restrict__ B2p,
    const float* __restrict__ convb, const float* __restrict__ inb,
    float* __restrict__ Qb, float* __restrict__ Kb, float* __restrict__ Vb) {
  __shared__ unsigned short Ps[16 * PSW];    // 34,816 B
  __shared__ unsigned short xhT[16 * 68];    //  2,176 B
  int t = threadIdx.x, w = t >> 6, l = t & 63;
  int n0 = blockIdx.x * 16;
  int d1 = l >> 2, d2 = d1 + 16, kc = l & 3;
  int col = l & 15, sub = l >> 4;
  int sw = col & 7;
  facc ac = {0.f, 0.f, 0.f, 0.f};

  for (int half = 0; half < 2; ++half) {
    int hoff = half * 32 + kc * 8;
    // ---- phase 1: each wave builds 4 node rows of this K-half of P ----
#pragma unroll 1
    for (int i4 = 0; i4 < 4; ++i4) {
      int m = w * 4 + i4;
      int n = n0 + m;
      int s0 = starts[n], s1 = starts[n + 1];
      float acc[16];
#pragma unroll
      for (int z = 0; z < 16; ++z) acc[z] = 0.f;
      float xs1 = 0.f, xs2 = 0.f;
      int i = s0;
      uint4 hp = {0, 0, 0, 0};
      float xa = 0.f, xb = 0.f;
      if (i < s1) {
        int sr = srcl[i];
        hp = *(const uint4*)(hes + (size_t)i * 64 + hoff);
        xa = x[sr * 32 + d1]; xb = x[sr * 32 + d2];
      }
      while (i < s1) {
        uint4 h = hp; float va = xa, vb = xb;
        int inx = i + 1;
        if (inx < s1) {
          int sr = srcl[inx];
          hp = *(const uint4*)(hes + (size_t)inx * 64 + hoff);
          xa = x[sr * 32 + d1]; xb = x[sr * 32 + d2];
        }
        FMA8(h, 0, va) FMA8(h, 8, vb)
        xs1 += va; xs2 += vb;
        i = inx;
      }
      int s = m & 7;
      uint4 o0, o1;
      o0.x = pk2(acc[0], acc[1]);   o0.y = pk2(acc[2], acc[3]);
      o0.z = pk2(acc[4], acc[5]);   o0.w = pk2(acc[6], acc[7]);
      o1.x = pk2(acc[8], acc[9]);   o1.y = pk2(acc[10], acc[11]);
      o1.z = pk2(acc[12], acc[13]); o1.w = pk2(acc[14], acc[15]);
      *(uint4*)(Ps + m * PSW + (l ^ s) * 8) = o0;
      *(uint4*)(Ps + m * PSW + ((l + 64) ^ s) * 8) = o1;
      if (kc == 0) {
        if (half == 0) {
          Ps[m * PSW + ((128 + (d1 >> 3)) ^ s) * 8 + (d1 & 7)] = f2bf(xs1);
          Ps[m * PSW + ((128 + (d2 >> 3)) ^ s) * 8 + (d2 & 7)] = f2bf(xs2);
        } else {
          int cnt = s1 - s0; if (cnt < 1) cnt = 1;
          Ps[m * PSW + ((128 + (d1 >> 3)) ^ s) * 8 + (d1 & 7)] =
              f2bf(x[n * 32 + d1] * (float)cnt);
          Ps[m * PSW + ((128 + (d2 >> 3)) ^ s) * 8 + (d2 & 7)] =
              f2bf(x[n * 32 + d2] * (float)cnt);
        }
      }
    }
    __syncthreads();
    // ---- phase 2: GEMM K-pass (33 kb), wave w owns col block w*16..+16 ----
    const bfrag* Bb = (const bfrag*)Bp + (half * 33) * 256 + w * 64 + l;
#pragma unroll 3
    for (int kb = 0; kb < 33; ++kb) {
      bfrag af = *(const bfrag*)(Ps + col * PSW + (((kb << 2) + sub) ^ sw) * 8);
      ac = __builtin_amdgcn_mfma_f32_16x16x32_bf16(af, Bb[kb * 256], ac, 0, 0, 0);
    }
    __syncthreads();
  }
  // ---- epilogue: mean + conv_b + relu -> xhT ----
  float cv = convb[w * 16 + col];
#pragma unroll
  for (int j = 0; j < 4; ++j) {
    int m = sub * 4 + j, n = n0 + m;
    int cnt = starts[n + 1] - starts[n]; if (cnt < 1) cnt = 1;
    float inv = 1.f / (float)cnt;
    xhT[m * 68 + w * 16 + col] = f2bf(fmaxf(ac[j] * inv + cv, 0.f));
  }
  __syncthreads();
  // ---- phase 3: QKV, wave w owns 3 of 12 col blocks ----
  bfrag af0 = *(const bfrag*)&xhT[col * 68 + sub * 8];
  bfrag af1 = *(const bfrag*)&xhT[col * 68 + 32 + sub * 8];
  const bfrag* B2b = (const bfrag*)B2p + l;
#pragma unroll
  for (int c3 = 0; c3 < 3; ++c3) {
    int cb = w * 3 + c3;
    facc qa = {0.f, 0.f, 0.f, 0.f};
    qa = __builtin_amdgcn_mfma_f32_16x16x32_bf16(af0, B2b[cb * 64], qa, 0, 0, 0);
    qa = __builtin_amdgcn_mfma_f32_16x16x32_bf16(af1, B2b[(12 + cb) * 64], qa, 0, 0, 0);
#pragma unroll
    for (int j = 0; j < 4; ++j) {
      int n = n0 + sub * 4 + j;
      int g = n / 200, p = n - g * 200;
      int c = cb * 16 + col;
      float v = qa[j] + inb[c];
      int part = c >> 6, rem = c & 63, hh = rem >> 4, dd = rem & 15;
      float* dst = (part == 0) ? Qb : (part == 1 ? Kb : Vb);
      dst[(((size_t)g * 4 + hh) * 200 + p) * 16 + dd] = v;
    }
  }
}

// ---------------- MFMA flash attention: one block per (graph, head) ----------------
__global__ __launch_bounds__(256) void k_attn(const float* __restrict__ Qb,
    const float* __restrict__ Kb, const float* __restrict__ Vb,
    float* __restrict__ ctx) {
  __shared__ unsigned short Ks[224 * 24];
  __shared__ unsigned short Vt[16 * 232];
  __shared__ unsigned short Pl[4][16 * 40];
  int t = threadIdx.x;
  size_t base = (size_t)blockIdx.x * 3200;
  for (int idx = t; idx < 224 * 16; idx += 256) {
    int row = idx >> 4, d = idx & 15;
    float kv = (row < 200) ? Kb[base + idx] : 0.f;
    float vv = (row < 200) ? Vb[base + idx] : 0.f;
    Ks[row * 24 + d] = f2bf(kv);
    Vt[d * 232 + row] = f2bf(vv);
  }
  __syncthreads();
  int w = t >> 6, l = t & 63;
  int sub = l >> 4, col = l & 15;
  for (int qt = w; qt < 13; qt += 4) {
    bfrag qf = {0, 0, 0, 0, 0, 0, 0, 0};
    int q = qt * 16 + col;
    if (sub < 2 && q < 200) {
      const float* qp = Qb + base + q * 16 + sub * 8;
      float4 qa = *(const float4*)qp;
      float4 qb = *(const float4*)(qp + 4);
      qf[0] = (short)f2bf(qa.x); qf[1] = (short)f2bf(qa.y);
      qf[2] = (short)f2bf(qa.z); qf[3] = (short)f2bf(qa.w);
      qf[4] = (short)f2bf(qb.x); qf[5] = (short)f2bf(qb.y);
      qf[6] = (short)f2bf(qb.z); qf[7] = (short)f2bf(qb.w);
    }
    facc o = {0.f, 0.f, 0.f, 0.f};
    float srow0 = 0.f, srow1 = 0.f, srow2 = 0.f, srow3 = 0.f;
    for (int kt2 = 0; kt2 < 7; ++kt2) {
      int kt0 = kt2 * 2, kt1 = kt0 + 1;
      bfrag kf0 = {0, 0, 0, 0, 0, 0, 0, 0};
      bfrag kf1 = {0, 0, 0, 0, 0, 0, 0, 0};
      if (sub < 2) {
        kf0 = *(const bfrag*)&Ks[(kt0 * 16 + col) * 24 + sub * 8];
        kf1 = *(const bfrag*)&Ks[(kt1 * 16 + col) * 24 + sub * 8];
      }
      facc z = {0.f, 0.f, 0.f, 0.f};
      facc s0 = __builtin_amdgcn_mfma_f32_16x16x32_bf16(qf, kf0, z, 0, 0, 0);
      facc s1 = __builtin_amdgcn_mfma_f32_16x16x32_bf16(qf, kf1, z, 0, 0, 0);
      bool ok0 = (kt0 * 16 + col) < 200;
      bool ok1 = (kt1 * 16 + col) < 200;
#pragma unroll
      for (int j = 0; j < 4; ++j) {
        float e0 = ok0 ? __expf(s0[j] * 0.25f) : 0.f;
        float e1 = ok1 ? __expf(s1[j] * 0.25f) : 0.f;
        if (j == 0) { srow0 += e0 + e1; } else if (j == 1) { srow1 += e0 + e1; }
        else if (j == 2) { srow2 += e0 + e1; } else { srow3 += e0 + e1; }
        int qr = (sub << 2) + j;
        Pl[w][qr * 40 + col] = f2bf(e0);
        Pl[w][qr * 40 + 16 + col] = f2bf(e1);
      }
      bfrag pf = *(const bfrag*)&Pl[w][col * 40 + sub * 8];
      bfrag vf = *(const bfrag*)&Vt[col * 232 + kt2 * 32 + sub * 8];
      o = __builtin_amdgcn_mfma_f32_16x16x32_bf16(pf, vf, o, 0, 0, 0);
    }
#pragma unroll
    for (int off = 1; off < 16; off <<= 1) {
      srow0 += __shfl_xor(srow0, off);
      srow1 += __shfl_xor(srow1, off);
      srow2 += __shfl_xor(srow2, off);
      srow3 += __shfl_xor(srow3, off);
    }
#pragma unroll
    for (int j = 0; j < 4; ++j) {
      int qq = qt * 16 + (sub << 2) + j;
      float sr = (j == 0) ? srow0 : (j == 1) ? srow1 : (j == 2) ? srow2 : srow3;
      if (qq < 200) ctx[base + qq * 16 + col] = o[j] / sr;
    }
  }
}

// ---------------- pool + MLP head ----------------
__global__ __launch_bounds__(64) void k_head(const float* __restrict__ ctx,
    const float* __restrict__ ow, const float* __restrict__ ob,
    const float* __restrict__ w1, const float* __restrict__ b1,
    const float* __restrict__ w2, const float* __restrict__ b2,
    float* __restrict__ out) {
  __shared__ float ms[64], es[64];
  int g = blockIdx.x, t = threadIdx.x;
  int hh = t >> 4, dd = t & 15;
  const float* cb = ctx + (((size_t)g * 4 + hh) * 200) * 16 + dd;
  float s = 0.f;
  for (int p = 0; p < 200; ++p) s += cb[p * 16];
  ms[t] = s * (1.f / 200.f);
  __syncthreads();
  float e = ob[t];
  for (int j = 0; j < 64; ++j) e += ow[t * 64 + j] * ms[j];
  es[t] = e;
  __syncthreads();
  float h1 = b1[t];
  for (int j = 0; j < 64; ++j) h1 += w1[t * 64 + j] * es[j];
  h1 = fmaxf(h1, 0.f);
  float pr = h1 * w2[t];
  for (int off = 32; off >= 1; off >>= 1) pr += __shfl_xor(pr, off);
  if (t == 0) out[g] = pr + b2[0];
}

extern "C" void kernel_launch(void* const* d_in, const int* in_sizes, int n_in,
                              void* d_out, int out_size, void* d_ws, size_t ws_size,
                              hipStream_t stream) {
  (void)in_sizes; (void)n_in;
  const float* x      = (const float*)d_in[0];
  const int*   eidx   = (const int*)d_in[1];
  const float* ea     = (const float*)d_in[2];
  const float* en_w1  = (const float*)d_in[4];
  const float* en_b1  = (const float*)d_in[5];
  const float* en_w2  = (const float*)d_in[6];
  const float* en_b2  = (const float*)d_in[7];
  const float* root_w = (const float*)d_in[8];
  const float* conv_b = (const float*)d_in[9];
  const float* in_w   = (const float*)d_in[10];
  const float* in_b   = (const float*)d_in[11];
  const float* out_w  = (const float*)d_in[12];
  const float* out_b  = (const float*)d_in[13];
  const float* l1w    = (const float*)d_in[14];
  const float* l1b    = (const float*)d_in[15];
  const float* l2w    = (const float*)d_in[16];
  const float* l2b    = (const float*)d_in[17];
  float* out = (float*)d_out;

  // ---- workspace layout (bytes) ----
  char* w = (char*)d_ws;
  unsigned short* hes = (unsigned short*)w;            // 20,480,000 (dst-sorted he)
  float* Qb  = (float*)(w + 20480000);
  float* Kb  = (float*)(w + 25600000);
  float* Vb  = (float*)(w + 30720000);
  float* ctx = (float*)(w + 35840000);                 // ends 40,960,000
  char* r3 = w + 40960000;
  unsigned short* Bp  = (unsigned short*)r3;             // 270,336
  unsigned short* B2p = (unsigned short*)(r3 + 270336);  // 24,576
  int* starts = (int*)(r3 + 270336 + 24576);
  int* perm   = starts + (N_N + 4);
  int* srcl   = perm + N_E;
  int* cursor = srcl + N_E;
  size_t need = 40960000 + 270336 + 24576
              + (size_t)(N_N + 4) * 4 + 2 * (size_t)N_E * 4 + (size_t)N_N * 4;
  if (ws_size < need || out_size < 100) return;

  hipMemsetAsync(cursor, 0, N_N * 4, stream);
  k_pack<<<580, 256, 0, stream>>>(en_w2, en_b2, root_w, in_w, Bp, B2p);
  k_hist<<<N_E / 256, 256, 0, stream>>>(eidx, cursor);
  k_scan<<<1, 1024, 0, stream>>>(cursor, starts);
  k_scatter<<<N_E / 256, 256, 0, stream>>>(eidx, cursor, perm, srcl);
  k_mlp1<<<5000, 256, 0, stream>>>(ea, en_w1, en_b1, perm, hes);
  k_fused<<<1250, 256, 0, stream>>>(x, hes, starts, srcl, Bp, B2p,
                                    conv_b, in_b, Qb, Kb, Vb);
  k_attn<<<400, 256, 0, stream>>>(Qb, Kb, Vb, ctx);
  k_head<<<100, 64, 0, stream>>>(ctx, out_w, out_b, l1w, l1b, l2w, l2b, out);
}

// Round 7
// 208.747 us; speedup vs baseline: 1.0202x; 1.0202x over previous
//
#include <hip/hip_runtime.h>
#include <math.h>

#define N_N 20000
#define N_E 160000
#define KA 2112   // A cols: 2048 (P) + 32 (xsum for b2) + 32 (x*cnt for root_w)
#define NKB 66

typedef __attribute__((ext_vector_type(8))) short bfrag;
typedef __attribute__((ext_vector_type(4))) float facc;

__device__ __forceinline__ unsigned short f2bf(float f) {
  union { float f; unsigned u; } v; v.f = f;
  unsigned u = v.u;
  return (unsigned short)((u + 0x7FFF + ((u >> 16) & 1)) >> 16);
}
__device__ __forceinline__ unsigned pk2(float a, float b) {
  return (unsigned)f2bf(a) | ((unsigned)f2bf(b) << 16);
}
__device__ __forceinline__ float bflo(unsigned u) {
  union { unsigned u; float f; } v; v.u = u << 16; return v.f;
}
__device__ __forceinline__ float bfhi(unsigned u) {
  union { unsigned u; float f; } v; v.u = u & 0xffff0000u; return v.f;
}

// ---------------- edge MLP layer 1 -> bf16 he, written PERMUTED to dst-sorted order ------
__global__ __launch_bounds__(256) void k_mlp1(const float* __restrict__ ea,
    const float* __restrict__ w1, const float* __restrict__ b1,
    const int* __restrict__ perm, unsigned short* __restrict__ hes) {
  int t = threadIdx.x, w = t >> 6, j = t & 63;
  int e0 = (blockIdx.x * 4 + w) * 8;
  float wr[16];
#pragma unroll
  for (int i = 0; i < 16; ++i) wr[i] = w1[j * 16 + i];
  float bj = b1[j];
#pragma unroll
  for (int q = 0; q < 8; ++q) {
    int e = e0 + q;
    const float* a = ea + (size_t)e * 16;
    float s = bj;
#pragma unroll
    for (int i = 0; i < 16; ++i) s += a[i] * wr[i];
    hes[(size_t)perm[e] * 64 + j] = f2bf(fmaxf(s, 0.f));
  }
}

// ---------------- CSR build by dst ----------------
__global__ __launch_bounds__(256) void k_hist(const int* __restrict__ eidx,
    int* __restrict__ cnt) {
  int e = blockIdx.x * 256 + threadIdx.x;
  atomicAdd(&cnt[eidx[N_E + e]], 1);
}

__global__ __launch_bounds__(1024) void k_scan(int* __restrict__ hist,
    int* __restrict__ starts) {
  __shared__ int part[1024];
  int t = threadIdx.x;
  const int CH = 20;
  int lo = t * CH;
  int hi = lo + CH; if (hi > N_N) hi = N_N;
  int s = 0;
  for (int i = lo; i < hi; ++i) s += hist[i];
  part[t] = s;
  __syncthreads();
  for (int off = 1; off < 1024; off <<= 1) {
    int v = (t >= off) ? part[t - off] : 0;
    __syncthreads();
    part[t] += v;
    __syncthreads();
  }
  int run = (t == 0) ? 0 : part[t - 1];
  for (int i = lo; i < hi; ++i) {
    int h = hist[i];
    starts[i] = run;
    hist[i] = run;          // cursor seed
    run += h;
  }
  if (t == 1023) starts[N_N] = part[1023];
}

__global__ __launch_bounds__(256) void k_scatter(const int* __restrict__ eidx,
    int* __restrict__ cur, int* __restrict__ perm, int* __restrict__ srcl) {
  int e = blockIdx.x * 256 + threadIdx.x;
  int dn = eidx[N_E + e];
  int pos = atomicAdd(&cur[dn], 1);
  perm[e] = pos;
  srcl[pos] = eidx[e];
}

// ---------------- pack B (gemm), B2 (qkv) fragment layouts (R5 layout) ----------------
__global__ __launch_bounds__(256) void k_pack(const float* __restrict__ w2,
    const float* __restrict__ b2f, const float* __restrict__ rootw,
    const float* __restrict__ inw,
    unsigned short* __restrict__ Bp, unsigned short* __restrict__ B2p) {
  int idx = blockIdx.x * 256 + threadIdx.x;
  if (idx < 135168) {
    int i = idx & 7, l = (idx >> 3) & 63, cbkb = idx >> 9;
    int cb = cbkb & 3, kb = cbkb >> 2;
    int r = kb * 32 + ((l >> 4) << 3) + i;
    int c = (cb << 4) + (l & 15);
    float v;
    if (r < 2048) { int d = r >> 6, k = r & 63; v = w2[((d << 6) + c) * 64 + k]; }
    else if (r < 2080) v = b2f[((r - 2048) << 6) + c];
    else v = rootw[((r - 2080) << 6) + c];
    Bp[idx] = f2bf(v);
  } else if (idx < 135168 + 12288) {
    int k2 = idx - 135168;
    int i = k2 & 7, l = (k2 >> 3) & 63, cbkb = k2 >> 9;
    int cb = cbkb % 12, kb = cbkb / 12;
    int r = kb * 32 + ((l >> 4) << 3) + i;
    int c = (cb << 4) + (l & 15);
    B2p[k2] = f2bf(inw[c * 64 + r]);
  }
}

// ---------------- FUSED: P-build (LDS) + MFMA GEMM + mean/bias/relu + QKV ----------------
// Block = 16 nodes. P in LDS, chunk-swizzled: chunk c of row m at chunk c^(m&7).
// Lane l owns chunks {l, l+64, l+128, l+192}; d0 = l>>3, hc = (l&7)*8.
// Edge loop: 2x-unrolled with 2-edge-deep register prefetch (stages A/B).
#define FMA8(hv, base, xv) \
  acc[base + 0] += xv * bflo(hv.x); acc[base + 1] += xv * bfhi(hv.x); \
  acc[base + 2] += xv * bflo(hv.y); acc[base + 3] += xv * bfhi(hv.y); \
  acc[base + 4] += xv * bflo(hv.z); acc[base + 5] += xv * bfhi(hv.z); \
  acc[base + 6] += xv * bflo(hv.w); acc[base + 7] += xv * bfhi(hv.w);

__global__ __launch_bounds__(256) void k_fused(const float* __restrict__ x,
    const unsigned short* __restrict__ hes, const int* __restrict__ starts,
    const int* __restrict__ srcl,
    const unsigned short* __restrict__ Bp, const unsigned short* __restrict__ B2p,
    const float* __restrict__ convb, const float* __restrict__ inb,
    float* __restrict__ Qb, float* __restrict__ Kb, float* __restrict__ Vb) {
  __shared__ unsigned short Ps[16 * KA];     // 67,584 B
  __shared__ unsigned short xhT[16 * 68];    //  2,176 B
  int t = threadIdx.x, w = t >> 6, l = t & 63;
  int n0 = blockIdx.x * 16;
  int d0 = l >> 3, hc = (l & 7) * 8;
  // ---- phase 1: each wave builds 4 node rows of P ----
#pragma unroll 1
  for (int i4 = 0; i4 < 4; ++i4) {
    int m = w * 4 + i4;
    int n = n0 + m;
    int s0 = starts[n], s1 = starts[n + 1];
    int len = s1 - s0;
    float acc[32];
#pragma unroll
    for (int z = 0; z < 32; ++z) acc[z] = 0.f;
    float xs = 0.f;
    const unsigned short* hrow = hes + (size_t)s0 * 64 + hc;
    uint4 hA = {0, 0, 0, 0}, hB = {0, 0, 0, 0};
    float a0 = 0.f, a1 = 0.f, a2 = 0.f, a3 = 0.f, as = 0.f;
    float b0 = 0.f, b1 = 0.f, b2 = 0.f, b3 = 0.f, bs = 0.f;
    if (len > 0) {
      int sr = srcl[s0];
      hA = *(const uint4*)(hrow);
      const float* xr = x + sr * 32;
      a0 = xr[d0]; a1 = xr[d0 + 8]; a2 = xr[d0 + 16]; a3 = xr[d0 + 24];
      as = (l < 32) ? xr[l] : 0.f;
    }
    if (len > 1) {
      int sr = srcl[s0 + 1];
      hB = *(const uint4*)(hrow + 64);
      const float* xr = x + sr * 32;
      b0 = xr[d0]; b1 = xr[d0 + 8]; b2 = xr[d0 + 16]; b3 = xr[d0 + 24];
      bs = (l < 32) ? xr[l] : 0.f;
    }
#pragma unroll 1
    for (int i = 0; i < len; i += 2) {
      uint4 cA = hA, cB = hB;
      float c0 = a0, c1 = a1, c2 = a2, c3 = a3, cs = as;
      float e0 = b0, e1 = b1, e2 = b2, e3 = b3, es = bs;
      if (i + 2 < len) {
        int sr = srcl[s0 + i + 2];
        hA = *(const uint4*)(hrow + (size_t)(i + 2) * 64);
        const float* xr = x + sr * 32;
        a0 = xr[d0]; a1 = xr[d0 + 8]; a2 = xr[d0 + 16]; a3 = xr[d0 + 24];
        as = (l < 32) ? xr[l] : 0.f;
      }
      if (i + 3 < len) {
        int sr = srcl[s0 + i + 3];
        hB = *(const uint4*)(hrow + (size_t)(i + 3) * 64);
        const float* xr = x + sr * 32;
        b0 = xr[d0]; b1 = xr[d0 + 8]; b2 = xr[d0 + 16]; b3 = xr[d0 + 24];
        bs = (l < 32) ? xr[l] : 0.f;
      }
      FMA8(cA, 0, c0) FMA8(cA, 8, c1) FMA8(cA, 16, c2) FMA8(cA, 24, c3)
      xs += cs;
      if (i + 1 < len) {
        FMA8(cB, 0, e0) FMA8(cB, 8, e1) FMA8(cB, 16, e2) FMA8(cB, 24, e3)
        xs += es;
      }
    }
    int s = m & 7;
#pragma unroll
    for (int q = 0; q < 4; ++q) {
      int sc = (l + 64 * q) ^ s;
      uint4 o;
      o.x = pk2(acc[q * 8 + 0], acc[q * 8 + 1]);
      o.y = pk2(acc[q * 8 + 2], acc[q * 8 + 3]);
      o.z = pk2(acc[q * 8 + 4], acc[q * 8 + 5]);
      o.w = pk2(acc[q * 8 + 6], acc[q * 8 + 7]);
      *(uint4*)(Ps + m * KA + sc * 8) = o;
    }
    if (l < 32) {
      int cnt = len; if (cnt < 1) cnt = 1;
      int c1 = (256 + (l >> 3)) ^ s, c2 = (260 + (l >> 3)) ^ s;
      Ps[m * KA + c1 * 8 + (l & 7)] = f2bf(xs);
      Ps[m * KA + c2 * 8 + (l & 7)] = f2bf(x[n * 32 + l] * (float)cnt);
    }
  }
  __syncthreads();
  // ---- phase 2: GEMM K-loop, wave w owns col block w*16..+16 ----
  int col = l & 15, sub = l >> 4;
  int sw = col & 7;
  const bfrag* Bb = (const bfrag*)Bp + w * 64 + l;
  facc ac = {0.f, 0.f, 0.f, 0.f};
#pragma unroll 4
  for (int kb = 0; kb < NKB; ++kb) {
    int sc = ((kb << 2) + sub) ^ sw;
    bfrag af = *(const bfrag*)(Ps + col * KA + sc * 8);
    ac = __builtin_amdgcn_mfma_f32_16x16x32_bf16(af, Bb[kb * 256], ac, 0, 0, 0);
  }
  float cv = convb[w * 16 + col];
#pragma unroll
  for (int j = 0; j < 4; ++j) {
    int m = sub * 4 + j, n = n0 + m;
    int cnt = starts[n + 1] - starts[n]; if (cnt < 1) cnt = 1;
    float inv = 1.f / (float)cnt;
    xhT[m * 68 + w * 16 + col] = f2bf(fmaxf(ac[j] * inv + cv, 0.f));
  }
  __syncthreads();
  // ---- phase 3: QKV, wave w owns 3 of 12 col blocks ----
  bfrag af0 = *(const bfrag*)&xhT[col * 68 + sub * 8];
  bfrag af1 = *(const bfrag*)&xhT[col * 68 + 32 + sub * 8];
  const bfrag* B2b = (const bfrag*)B2p + l;
#pragma unroll
  for (int c3 = 0; c3 < 3; ++c3) {
    int cb = w * 3 + c3;
    facc qa = {0.f, 0.f, 0.f, 0.f};
    qa = __builtin_amdgcn_mfma_f32_16x16x32_bf16(af0, B2b[cb * 64], qa, 0, 0, 0);
    qa = __builtin_amdgcn_mfma_f32_16x16x32_bf16(af1, B2b[(12 + cb) * 64], qa, 0, 0, 0);
#pragma unroll
    for (int j = 0; j < 4; ++j) {
      int n = n0 + sub * 4 + j;
      int g = n / 200, p = n - g * 200;
      int c = cb * 16 + col;
      float v = qa[j] + inb[c];
      int part = c >> 6, rem = c & 63, hh = rem >> 4, dd = rem & 15;
      float* dst = (part == 0) ? Qb : (part == 1 ? Kb : Vb);
      dst[(((size_t)g * 4 + hh) * 200 + p) * 16 + dd] = v;
    }
  }
}

// ---------------- MFMA flash attention: one block per (graph, head) ----------------
__global__ __launch_bounds__(256) void k_attn(const float* __restrict__ Qb,
    const float* __restrict__ Kb, const float* __restrict__ Vb,
    float* __restrict__ ctx) {
  __shared__ unsigned short Ks[224 * 24];
  __shared__ unsigned short Vt[16 * 232];
  __shared__ unsigned short Pl[4][16 * 40];
  int t = threadIdx.x;
  size_t base = (size_t)blockIdx.x * 3200;
  for (int idx = t; idx < 224 * 16; idx += 256) {
    int row = idx >> 4, d = idx & 15;
    float kv = (row < 200) ? Kb[base + idx] : 0.f;
    float vv = (row < 200) ? Vb[base + idx] : 0.f;
    Ks[row * 24 + d] = f2bf(kv);
    Vt[d * 232 + row] = f2bf(vv);
  }
  __syncthreads();
  int w = t >> 6, l = t & 63;
  int sub = l >> 4, col = l & 15;
  for (int qt = w; qt < 13; qt += 4) {
    bfrag qf = {0, 0, 0, 0, 0, 0, 0, 0};
    int q = qt * 16 + col;
    if (sub < 2 && q < 200) {
      const float* qp = Qb + base + q * 16 + sub * 8;
      float4 qa = *(const float4*)qp;
      float4 qb = *(const float4*)(qp + 4);
      qf[0] = (short)f2bf(qa.x); qf[1] = (short)f2bf(qa.y);
      qf[2] = (short)f2bf(qa.z); qf[3] = (short)f2bf(qa.w);
      qf[4] = (short)f2bf(qb.x); qf[5] = (short)f2bf(qb.y);
      qf[6] = (short)f2bf(qb.z); qf[7] = (short)f2bf(qb.w);
    }
    facc o = {0.f, 0.f, 0.f, 0.f};
    float srow0 = 0.f, srow1 = 0.f, srow2 = 0.f, srow3 = 0.f;
    for (int kt2 = 0; kt2 < 7; ++kt2) {
      int kt0 = kt2 * 2, kt1 = kt0 + 1;
      bfrag kf0 = {0, 0, 0, 0, 0, 0, 0, 0};
      bfrag kf1 = {0, 0, 0, 0, 0, 0, 0, 0};
      if (sub < 2) {
        kf0 = *(const bfrag*)&Ks[(kt0 * 16 + col) * 24 + sub * 8];
        kf1 = *(const bfrag*)&Ks[(kt1 * 16 + col) * 24 + sub * 8];
      }
      facc z = {0.f, 0.f, 0.f, 0.f};
      facc s0 = __builtin_amdgcn_mfma_f32_16x16x32_bf16(qf, kf0, z, 0, 0, 0);
      facc s1 = __builtin_amdgcn_mfma_f32_16x16x32_bf16(qf, kf1, z, 0, 0, 0);
      bool ok0 = (kt0 * 16 + col) < 200;
      bool ok1 = (kt1 * 16 + col) < 200;
#pragma unroll
      for (int j = 0; j < 4; ++j) {
        float e0 = ok0 ? __expf(s0[j] * 0.25f) : 0.f;
        float e1 = ok1 ? __expf(s1[j] * 0.25f) : 0.f;
        if (j == 0) { srow0 += e0 + e1; } else if (j == 1) { srow1 += e0 + e1; }
        else if (j == 2) { srow2 += e0 + e1; } else { srow3 += e0 + e1; }
        int qr = (sub << 2) + j;
        Pl[w][qr * 40 + col] = f2bf(e0);
        Pl[w][qr * 40 + 16 + col] = f2bf(e1);
      }
      bfrag pf = *(const bfrag*)&Pl[w][col * 40 + sub * 8];
      bfrag vf = *(const bfrag*)&Vt[col * 232 + kt2 * 32 + sub * 8];
      o = __builtin_amdgcn_mfma_f32_16x16x32_bf16(pf, vf, o, 0, 0, 0);
    }
#pragma unroll
    for (int off = 1; off < 16; off <<= 1) {
      srow0 += __shfl_xor(srow0, off);
      srow1 += __shfl_xor(srow1, off);
      srow2 += __shfl_xor(srow2, off);
      srow3 += __shfl_xor(srow3, off);
    }
#pragma unroll
    for (int j = 0; j < 4; ++j) {
      int qq = qt * 16 + (sub << 2) + j;
      float sr = (j == 0) ? srow0 : (j == 1) ? srow1 : (j == 2) ? srow2 : srow3;
      if (qq < 200) ctx[base + qq * 16 + col] = o[j] / sr;
    }
  }
}

// ---------------- pool + MLP head (256 threads: 4-way split pool) ----------------
__global__ __launch_bounds__(256) void k_head(const float* __restrict__ ctx,
    const float* __restrict__ ow, const float* __restrict__ ob,
    const float* __restrict__ w1, const float* __restrict__ b1,
    const float* __restrict__ w2, const float* __restrict__ b2,
    float* __restrict__ out) {
  __shared__ float pool[4][64];
  __shared__ float ms[64], es[64];
  int g = blockIdx.x, t = threadIdx.x;
  int q = t >> 6, c = t & 63;
  int hh = c >> 4, dd = c & 15;
  const float* cb = ctx + (((size_t)g * 4 + hh) * 200) * 16 + dd;
  float s = 0.f;
  for (int p = q; p < 200; p += 4) s += cb[p * 16];
  pool[q][c] = s;
  __syncthreads();
  if (t < 64) {
    float sm = pool[0][t] + pool[1][t] + pool[2][t] + pool[3][t];
    ms[t] = sm * (1.f / 200.f);
  }
  __syncthreads();
  if (t < 64) {
    float e = ob[t];
    for (int j = 0; j < 64; ++j) e += ow[t * 64 + j] * ms[j];
    es[t] = e;
  }
  __syncthreads();
  if (t < 64) {
    float h1 = b1[t];
    for (int j = 0; j < 64; ++j) h1 += w1[t * 64 + j] * es[j];
    h1 = fmaxf(h1, 0.f);
    float pr = h1 * w2[t];
    for (int off = 32; off >= 1; off >>= 1) pr += __shfl_xor(pr, off);
    if (t == 0) out[g] = pr + b2[0];
  }
}

extern "C" void kernel_launch(void* const* d_in, const int* in_sizes, int n_in,
                              void* d_out, int out_size, void* d_ws, size_t ws_size,
                              hipStream_t stream) {
  (void)in_sizes; (void)n_in;
  const float* x      = (const float*)d_in[0];
  const int*   eidx   = (const int*)d_in[1];
  const float* ea     = (const float*)d_in[2];
  const float* en_w1  = (const float*)d_in[4];
  const float* en_b1  = (const float*)d_in[5];
  const float* en_w2  = (const float*)d_in[6];
  const float* en_b2  = (const float*)d_in[7];
  const float* root_w = (const float*)d_in[8];
  const float* conv_b = (const float*)d_in[9];
  const float* in_w   = (const float*)d_in[10];
  const float* in_b   = (const float*)d_in[11];
  const float* out_w  = (const float*)d_in[12];
  const float* out_b  = (const float*)d_in[13];
  const float* l1w    = (const float*)d_in[14];
  const float* l1b    = (const float*)d_in[15];
  const float* l2w    = (const float*)d_in[16];
  const float* l2b    = (const float*)d_in[17];
  float* out = (float*)d_out;

  // ---- workspace layout (bytes) ----
  char* w = (char*)d_ws;
  unsigned short* hes = (unsigned short*)w;            // 20,480,000 (dst-sorted he)
  float* Qb  = (float*)(w + 20480000);
  float* Kb  = (float*)(w + 25600000);
  float* Vb  = (float*)(w + 30720000);
  float* ctx = (float*)(w + 35840000);                 // ends 40,960,000
  char* r3 = w + 40960000;
  unsigned short* Bp  = (unsigned short*)r3;             // 270,336
  unsigned short* B2p = (unsigned short*)(r3 + 270336);  // 24,576
  int* starts = (int*)(r3 + 270336 + 24576);
  int* perm   = starts + (N_N + 4);
  int* srcl   = perm + N_E;
  int* cursor = srcl + N_E;
  size_t need = 40960000 + 270336 + 24576
              + (size_t)(N_N + 4) * 4 + 2 * (size_t)N_E * 4 + (size_t)N_N * 4;
  if (ws_size < need || out_size < 100) return;

  hipMemsetAsync(cursor, 0, N_N * 4, stream);
  k_pack<<<580, 256, 0, stream>>>(en_w2, en_b2, root_w, in_w, Bp, B2p);
  k_hist<<<N_E / 256, 256, 0, stream>>>(eidx, cursor);
  k_scan<<<1, 1024, 0, stream>>>(cursor, starts);
  k_scatter<<<N_E / 256, 256, 0, stream>>>(eidx, cursor, perm, srcl);
  k_mlp1<<<5000, 256, 0, stream>>>(ea, en_w1, en_b1, perm, hes);
  k_fused<<<1250, 256, 0, stream>>>(x, hes, starts, srcl, Bp, B2p,
                                    conv_b, in_b, Qb, Kb, Vb);
  k_attn<<<400, 256, 0, stream>>>(Qb, Kb, Vb, ctx);
  k_head<<<100, 256, 0, stream>>>(ctx, out_w, out_b, l1w, l1b, l2w, l2b, out);
}

// Round 8
// 200.015 us; speedup vs baseline: 1.0648x; 1.0437x over previous
//
#include <hip/hip_runtime.h>
#include <math.h>

#define N_N 20000
#define N_E 160000
#define KA 2112   // A cols: 2048 (P) + 32 (xsum for b2) + 32 (x*cnt for root_w)
#define NKB 66

typedef __attribute__((ext_vector_type(8))) short bfrag;
typedef __attribute__((ext_vector_type(4))) float facc;

__device__ __forceinline__ unsigned short f2bf(float f) {
  union { float f; unsigned u; } v; v.f = f;
  unsigned u = v.u;
  return (unsigned short)((u + 0x7FFF + ((u >> 16) & 1)) >> 16);
}
__device__ __forceinline__ unsigned pk2(float a, float b) {
  return (unsigned)f2bf(a) | ((unsigned)f2bf(b) << 16);
}
__device__ __forceinline__ float bflo(unsigned u) {
  union { unsigned u; float f; } v; v.u = u << 16; return v.f;
}
__device__ __forceinline__ float bfhi(unsigned u) {
  union { unsigned u; float f; } v; v.u = u & 0xffff0000u; return v.f;
}

// ---------------- edge MLP layer 1 -> bf16 he, written PERMUTED to dst-sorted order ------
__global__ __launch_bounds__(256) void k_mlp1(const float* __restrict__ ea,
    const float* __restrict__ w1, const float* __restrict__ b1,
    const int* __restrict__ perm, unsigned short* __restrict__ hes) {
  int t = threadIdx.x, w = t >> 6, j = t & 63;
  int e0 = (blockIdx.x * 4 + w) * 8;
  float wr[16];
#pragma unroll
  for (int i = 0; i < 16; ++i) wr[i] = w1[j * 16 + i];
  float bj = b1[j];
#pragma unroll
  for (int q = 0; q < 8; ++q) {
    int e = e0 + q;
    const float* a = ea + (size_t)e * 16;
    float s = bj;
#pragma unroll
    for (int i = 0; i < 16; ++i) s += a[i] * wr[i];
    hes[(size_t)perm[e] * 64 + j] = f2bf(fmaxf(s, 0.f));
  }
}

// ---------------- CSR build by dst ----------------
__global__ __launch_bounds__(256) void k_hist(const int* __restrict__ eidx,
    int* __restrict__ cnt) {
  int e = blockIdx.x * 256 + threadIdx.x;
  atomicAdd(&cnt[eidx[N_E + e]], 1);
}

__global__ __launch_bounds__(1024) void k_scan(int* __restrict__ hist,
    int* __restrict__ starts) {
  __shared__ int part[1024];
  int t = threadIdx.x;
  const int CH = 20;
  int lo = t * CH;
  int hi = lo + CH; if (hi > N_N) hi = N_N;
  int s = 0;
  for (int i = lo; i < hi; ++i) s += hist[i];
  part[t] = s;
  __syncthreads();
  for (int off = 1; off < 1024; off <<= 1) {
    int v = (t >= off) ? part[t - off] : 0;
    __syncthreads();
    part[t] += v;
    __syncthreads();
  }
  int run = (t == 0) ? 0 : part[t - 1];
  for (int i = lo; i < hi; ++i) {
    int h = hist[i];
    starts[i] = run;
    hist[i] = run;          // cursor seed
    run += h;
  }
  if (t == 1023) starts[N_N] = part[1023];
}

__global__ __launch_bounds__(256) void k_scatter(const int* __restrict__ eidx,
    int* __restrict__ cur, int* __restrict__ perm, int* __restrict__ srcl) {
  int e = blockIdx.x * 256 + threadIdx.x;
  int dn = eidx[N_E + e];
  int pos = atomicAdd(&cur[dn], 1);
  perm[e] = pos;
  srcl[pos] = eidx[e];
}

// ---------------- pack B (gemm), B2 (qkv) fragment layouts ----------------
__global__ __launch_bounds__(256) void k_pack(const float* __restrict__ w2,
    const float* __restrict__ b2f, const float* __restrict__ rootw,
    const float* __restrict__ inw,
    unsigned short* __restrict__ Bp, unsigned short* __restrict__ B2p) {
  int idx = blockIdx.x * 256 + threadIdx.x;
  if (idx < 135168) {
    int i = idx & 7, l = (idx >> 3) & 63, cbkb = idx >> 9;
    int cb = cbkb & 3, kb = cbkb >> 2;
    int r = kb * 32 + ((l >> 4) << 3) + i;
    int c = (cb << 4) + (l & 15);
    float v;
    if (r < 2048) { int d = r >> 6, k = r & 63; v = w2[((d << 6) + c) * 64 + k]; }
    else if (r < 2080) v = b2f[((r - 2048) << 6) + c];
    else v = rootw[((r - 2080) << 6) + c];
    Bp[idx] = f2bf(v);
  } else if (idx < 135168 + 12288) {
    int k2 = idx - 135168;
    int i = k2 & 7, l = (k2 >> 3) & 63, cbkb = k2 >> 9;
    int cb = cbkb % 12, kb = cbkb / 12;
    int r = kb * 32 + ((l >> 4) << 3) + i;
    int c = (cb << 4) + (l & 15);
    B2p[k2] = f2bf(inw[c * 64 + r]);
  }
}

// ---------------- FUSED: LDS-staged P-build + MFMA GEMM + mean/bias/relu + QKV -----------
// Block = 8 nodes, wave = 2 nodes. Per 32-edge chunk: stage he (coalesced) + x (gather)
// into wave-private LDS, then consume (2x ds_read_b128 + 32 FMA per edge).
// Lane l: d-range 4*(l>>3)..+4 (di), k-range (l&7)*8..+8 (ki). acc[di*8+ki].
// Ps swizzle: chunk c of row m stored at chunk c ^ ((c>>5)&7) ^ m.
#define FMA8(hv, base, xv) \
  acc[base + 0] += xv * bflo(hv.x); acc[base + 1] += xv * bfhi(hv.x); \
  acc[base + 2] += xv * bflo(hv.y); acc[base + 3] += xv * bfhi(hv.y); \
  acc[base + 4] += xv * bflo(hv.z); acc[base + 5] += xv * bfhi(hv.z); \
  acc[base + 6] += xv * bflo(hv.w); acc[base + 7] += xv * bfhi(hv.w);

__global__ __launch_bounds__(256) void k_fused(const float* __restrict__ x,
    const unsigned short* __restrict__ hes, const int* __restrict__ starts,
    const int* __restrict__ srcl,
    const unsigned short* __restrict__ Bp, const unsigned short* __restrict__ B2p,
    const float* __restrict__ convb, const float* __restrict__ inb,
    float* __restrict__ Qb, float* __restrict__ Kb, float* __restrict__ Vb) {
  __shared__ unsigned short Ps[8 * KA];        // 33,792 B
  __shared__ unsigned short Hs[4][32 * 64];    // 16,384 B
  __shared__ float Xs[4][32 * 32];             // 16,384 B
  __shared__ unsigned short xhT[8 * 68];       //  1,088 B
  int t = threadIdx.x, w = t >> 6, l = t & 63;
  int n0 = blockIdx.x * 8;
  int g8 = l >> 3, o8 = l & 7;
  unsigned short* Hw = Hs[w];
  float* Xw = Xs[w];

  // ---- phase 1: wave builds its 2 nodes' P rows via staged chunks ----
  int na = n0 + w * 2;
  int sA = starts[na], sM = starts[na + 1], sB = starts[na + 2];
  float acc[32];
#pragma unroll
  for (int z = 0; z < 32; ++z) acc[z] = 0.f;
  float4 xs4 = {0.f, 0.f, 0.f, 0.f};
  int curm = w * 2;
  int ns = sA, ce = sM;

  auto flushnode = [&]() {
    int m = curm;
    int cnt = ce - ns; if (cnt < 1) cnt = 1;
#pragma unroll
    for (int di = 0; di < 4; ++di) {
      uint4 o;
      o.x = pk2(acc[di * 8 + 0], acc[di * 8 + 1]);
      o.y = pk2(acc[di * 8 + 2], acc[di * 8 + 3]);
      o.z = pk2(acc[di * 8 + 4], acc[di * 8 + 5]);
      o.w = pk2(acc[di * 8 + 6], acc[di * 8 + 7]);
      int c = (4 * g8 + di) * 8 + o8;
      int sc = c ^ ((c >> 5) & 7) ^ m;
      *(uint4*)(Ps + m * KA + sc * 8) = o;
    }
    if (o8 < 4) {
      int d = 4 * g8 + o8;
      float xsv = (o8 == 0) ? xs4.x : (o8 == 1) ? xs4.y : (o8 == 2) ? xs4.z : xs4.w;
      int c1 = 256 + (d >> 3);
      int s1c = c1 ^ ((c1 >> 5) & 7) ^ m;
      Ps[m * KA + s1c * 8 + (d & 7)] = f2bf(xsv);
      float xnv = x[(size_t)(n0 + m) * 32 + d];
      int c2 = 260 + (d >> 3);
      int s2c = c2 ^ ((c2 >> 5) & 7) ^ m;
      Ps[m * KA + s2c * 8 + (d & 7)] = f2bf(xnv * (float)cnt);
    }
#pragma unroll
    for (int z = 0; z < 32; ++z) acc[z] = 0.f;
    xs4.x = 0.f; xs4.y = 0.f; xs4.z = 0.f; xs4.w = 0.f;
    curm++; ns = ce; ce = sB;
  };

#pragma unroll 1
  for (int c0 = sA; c0 < sB; c0 += 32) {
    int cc = sB - c0; if (cc > 32) cc = 32;
    int srv = 0;
    if (l < 32 && c0 + l < sB) srv = srcl[c0 + l];
    // stage he: 8 rows x 128B per instr, coalesced
#pragma unroll
    for (int q = 0; q < 4; ++q) {
      int r = q * 8 + g8;
      uint4 hv = {0, 0, 0, 0};
      if (c0 + r < sB) hv = *(const uint4*)(hes + (size_t)(c0 + r) * 64 + o8 * 8);
      *(uint4*)&Hw[r * 64 + o8 * 8] = hv;
    }
    // stage x: gather 8 rows x 128B per instr
#pragma unroll
    for (int q = 0; q < 4; ++q) {
      int r = q * 8 + g8;
      int sr = __shfl(srv, r);
      float4 xv = {0.f, 0.f, 0.f, 0.f};
      if (c0 + r < sB) xv = *(const float4*)(x + (size_t)sr * 32 + o8 * 4);
      *(float4*)&Xw[r * 32 + o8 * 4] = xv;
    }
    // consume from LDS
#pragma unroll 1
    for (int i = 0; i < cc; ++i) {
      int gi = c0 + i;
      while (gi == ce) flushnode();
      float4 xv = *(const float4*)&Xw[i * 32 + g8 * 4];
      uint4 hv = *(const uint4*)&Hw[i * 64 + o8 * 8];
      FMA8(hv, 0, xv.x) FMA8(hv, 8, xv.y) FMA8(hv, 16, xv.z) FMA8(hv, 24, xv.w)
      xs4.x += xv.x; xs4.y += xv.y; xs4.z += xv.z; xs4.w += xv.w;
    }
  }
  while (curm <= w * 2 + 1) flushnode();
  __syncthreads();

  // ---- phase 2: GEMM K-loop, wave w owns col block w*16..+16, M=8 ----
  int col = l & 15, sub = l >> 4;
  int arow = col & 7;
  const bfrag* Bb = (const bfrag*)Bp + w * 64 + l;
  facc ac = {0.f, 0.f, 0.f, 0.f};
#pragma unroll 6
  for (int kb = 0; kb < NKB; ++kb) {
    int c = (kb << 2) + sub;
    int sc = c ^ ((c >> 5) & 7) ^ arow;
    bfrag af = *(const bfrag*)(Ps + arow * KA + sc * 8);
    ac = __builtin_amdgcn_mfma_f32_16x16x32_bf16(af, Bb[kb * 256], ac, 0, 0, 0);
  }
  float cv = convb[w * 16 + col];
#pragma unroll
  for (int j = 0; j < 4; ++j) {
    int m = sub * 4 + j;
    if (m < 8) {
      int n = n0 + m;
      int cnt = starts[n + 1] - starts[n]; if (cnt < 1) cnt = 1;
      float inv = 1.f / (float)cnt;
      xhT[m * 68 + w * 16 + col] = f2bf(fmaxf(ac[j] * inv + cv, 0.f));
    }
  }
  __syncthreads();

  // ---- phase 3: QKV, wave w owns 3 of 12 col blocks, M=8 ----
  bfrag af0 = *(const bfrag*)&xhT[(col & 7) * 68 + sub * 8];
  bfrag af1 = *(const bfrag*)&xhT[(col & 7) * 68 + 32 + sub * 8];
  const bfrag* B2b = (const bfrag*)B2p + l;
#pragma unroll
  for (int c3 = 0; c3 < 3; ++c3) {
    int cb = w * 3 + c3;
    facc qa = {0.f, 0.f, 0.f, 0.f};
    qa = __builtin_amdgcn_mfma_f32_16x16x32_bf16(af0, B2b[cb * 64], qa, 0, 0, 0);
    qa = __builtin_amdgcn_mfma_f32_16x16x32_bf16(af1, B2b[(12 + cb) * 64], qa, 0, 0, 0);
#pragma unroll
    for (int j = 0; j < 4; ++j) {
      int m = sub * 4 + j;
      if (m < 8) {
        int n = n0 + m;
        int g = n / 200, p = n - g * 200;
        int c = cb * 16 + col;
        float v = qa[j] + inb[c];
        int part = c >> 6, rem = c & 63, hh = rem >> 4, dd = rem & 15;
        float* dst = (part == 0) ? Qb : (part == 1 ? Kb : Vb);
        dst[(((size_t)g * 4 + hh) * 200 + p) * 16 + dd] = v;
      }
    }
  }
}

// ---------------- MFMA flash attention: one block per (graph, head) ----------------
__global__ __launch_bounds__(256) void k_attn(const float* __restrict__ Qb,
    const float* __restrict__ Kb, const float* __restrict__ Vb,
    float* __restrict__ ctx) {
  __shared__ unsigned short Ks[224 * 24];
  __shared__ unsigned short Vt[16 * 232];
  __shared__ unsigned short Pl[4][16 * 40];
  int t = threadIdx.x;
  size_t base = (size_t)blockIdx.x * 3200;
  for (int idx = t; idx < 224 * 16; idx += 256) {
    int row = idx >> 4, d = idx & 15;
    float kv = (row < 200) ? Kb[base + idx] : 0.f;
    float vv = (row < 200) ? Vb[base + idx] : 0.f;
    Ks[row * 24 + d] = f2bf(kv);
    Vt[d * 232 + row] = f2bf(vv);
  }
  __syncthreads();
  int w = t >> 6, l = t & 63;
  int sub = l >> 4, col = l & 15;
  for (int qt = w; qt < 13; qt += 4) {
    bfrag qf = {0, 0, 0, 0, 0, 0, 0, 0};
    int q = qt * 16 + col;
    if (sub < 2 && q < 200) {
      const float* qp = Qb + base + q * 16 + sub * 8;
      float4 qa = *(const float4*)qp;
      float4 qb = *(const float4*)(qp + 4);
      qf[0] = (short)f2bf(qa.x); qf[1] = (short)f2bf(qa.y);
      qf[2] = (short)f2bf(qa.z); qf[3] = (short)f2bf(qa.w);
      qf[4] = (short)f2bf(qb.x); qf[5] = (short)f2bf(qb.y);
      qf[6] = (short)f2bf(qb.z); qf[7] = (short)f2bf(qb.w);
    }
    facc o = {0.f, 0.f, 0.f, 0.f};
    float srow0 = 0.f, srow1 = 0.f, srow2 = 0.f, srow3 = 0.f;
    for (int kt2 = 0; kt2 < 7; ++kt2) {
      int kt0 = kt2 * 2, kt1 = kt0 + 1;
      bfrag kf0 = {0, 0, 0, 0, 0, 0, 0, 0};
      bfrag kf1 = {0, 0, 0, 0, 0, 0, 0, 0};
      if (sub < 2) {
        kf0 = *(const bfrag*)&Ks[(kt0 * 16 + col) * 24 + sub * 8];
        kf1 = *(const bfrag*)&Ks[(kt1 * 16 + col) * 24 + sub * 8];
      }
      facc z = {0.f, 0.f, 0.f, 0.f};
      facc s0 = __builtin_amdgcn_mfma_f32_16x16x32_bf16(qf, kf0, z, 0, 0, 0);
      facc s1 = __builtin_amdgcn_mfma_f32_16x16x32_bf16(qf, kf1, z, 0, 0, 0);
      bool ok0 = (kt0 * 16 + col) < 200;
      bool ok1 = (kt1 * 16 + col) < 200;
#pragma unroll
      for (int j = 0; j < 4; ++j) {
        float e0 = ok0 ? __expf(s0[j] * 0.25f) : 0.f;
        float e1 = ok1 ? __expf(s1[j] * 0.25f) : 0.f;
        if (j == 0) { srow0 += e0 + e1; } else if (j == 1) { srow1 += e0 + e1; }
        else if (j == 2) { srow2 += e0 + e1; } else { srow3 += e0 + e1; }
        int qr = (sub << 2) + j;
        Pl[w][qr * 40 + col] = f2bf(e0);
        Pl[w][qr * 40 + 16 + col] = f2bf(e1);
      }
      bfrag pf = *(const bfrag*)&Pl[w][col * 40 + sub * 8];
      bfrag vf = *(const bfrag*)&Vt[col * 232 + kt2 * 32 + sub * 8];
      o = __builtin_amdgcn_mfma_f32_16x16x32_bf16(pf, vf, o, 0, 0, 0);
    }
#pragma unroll
    for (int off = 1; off < 16; off <<= 1) {
      srow0 += __shfl_xor(srow0, off);
      srow1 += __shfl_xor(srow1, off);
      srow2 += __shfl_xor(srow2, off);
      srow3 += __shfl_xor(srow3, off);
    }
#pragma unroll
    for (int j = 0; j < 4; ++j) {
      int qq = qt * 16 + (sub << 2) + j;
      float sr = (j == 0) ? srow0 : (j == 1) ? srow1 : (j == 2) ? srow2 : srow3;
      if (qq < 200) ctx[base + qq * 16 + col] = o[j] / sr;
    }
  }
}

// ---------------- pool + MLP head (256 threads: 4-way split pool) ----------------
__global__ __launch_bounds__(256) void k_head(const float* __restrict__ ctx,
    const float* __restrict__ ow, const float* __restrict__ ob,
    const float* __restrict__ w1, const float* __restrict__ b1,
    const float* __restrict__ w2, const float* __restrict__ b2,
    float* __restrict__ out) {
  __shared__ float pool[4][64];
  __shared__ float ms[64], es[64];
  int g = blockIdx.x, t = threadIdx.x;
  int q = t >> 6, c = t & 63;
  int hh = c >> 4, dd = c & 15;
  const float* cb = ctx + (((size_t)g * 4 + hh) * 200) * 16 + dd;
  float s = 0.f;
  for (int p = q; p < 200; p += 4) s += cb[p * 16];
  pool[q][c] = s;
  __syncthreads();
  if (t < 64) {
    float sm = pool[0][t] + pool[1][t] + pool[2][t] + pool[3][t];
    ms[t] = sm * (1.f / 200.f);
  }
  __syncthreads();
  if (t < 64) {
    float e = ob[t];
    for (int j = 0; j < 64; ++j) e += ow[t * 64 + j] * ms[j];
    es[t] = e;
  }
  __syncthreads();
  if (t < 64) {
    float h1 = b1[t];
    for (int j = 0; j < 64; ++j) h1 += w1[t * 64 + j] * es[j];
    h1 = fmaxf(h1, 0.f);
    float pr = h1 * w2[t];
    for (int off = 32; off >= 1; off >>= 1) pr += __shfl_xor(pr, off);
    if (t == 0) out[g] = pr + b2[0];
  }
}

extern "C" void kernel_launch(void* const* d_in, const int* in_sizes, int n_in,
                              void* d_out, int out_size, void* d_ws, size_t ws_size,
                              hipStream_t stream) {
  (void)in_sizes; (void)n_in;
  const float* x      = (const float*)d_in[0];
  const int*   eidx   = (const int*)d_in[1];
  const float* ea     = (const float*)d_in[2];
  const float* en_w1  = (const float*)d_in[4];
  const float* en_b1  = (const float*)d_in[5];
  const float* en_w2  = (const float*)d_in[6];
  const float* en_b2  = (const float*)d_in[7];
  const float* root_w = (const float*)d_in[8];
  const float* conv_b = (const float*)d_in[9];
  const float* in_w   = (const float*)d_in[10];
  const float* in_b   = (const float*)d_in[11];
  const float* out_w  = (const float*)d_in[12];
  const float* out_b  = (const float*)d_in[13];
  const float* l1w    = (const float*)d_in[14];
  const float* l1b    = (const float*)d_in[15];
  const float* l2w    = (const float*)d_in[16];
  const float* l2b    = (const float*)d_in[17];
  float* out = (float*)d_out;

  // ---- workspace layout (bytes) ----
  char* w = (char*)d_ws;
  unsigned short* hes = (unsigned short*)w;            // 20,480,000 (dst-sorted he)
  float* Qb  = (float*)(w + 20480000);
  float* Kb  = (float*)(w + 25600000);
  float* Vb  = (float*)(w + 30720000);
  float* ctx = (float*)(w + 35840000);                 // ends 40,960,000
  char* r3 = w + 40960000;
  unsigned short* Bp  = (unsigned short*)r3;             // 270,336
  unsigned short* B2p = (unsigned short*)(r3 + 270336);  // 24,576
  int* starts = (int*)(r3 + 270336 + 24576);
  int* perm   = starts + (N_N + 4);
  int* srcl   = perm + N_E;
  int* cursor = srcl + N_E;
  size_t need = 40960000 + 270336 + 24576
              + (size_t)(N_N + 4) * 4 + 2 * (size_t)N_E * 4 + (size_t)N_N * 4;
  if (ws_size < need || out_size < 100) return;

  hipMemsetAsync(cursor, 0, N_N * 4, stream);
  k_pack<<<580, 256, 0, stream>>>(en_w2, en_b2, root_w, in_w, Bp, B2p);
  k_hist<<<N_E / 256, 256, 0, stream>>>(eidx, cursor);
  k_scan<<<1, 1024, 0, stream>>>(cursor, starts);
  k_scatter<<<N_E / 256, 256, 0, stream>>>(eidx, cursor, perm, srcl);
  k_mlp1<<<5000, 256, 0, stream>>>(ea, en_w1, en_b1, perm, hes);
  k_fused<<<2500, 256, 0, stream>>>(x, hes, starts, srcl, Bp, B2p,
                                    conv_b, in_b, Qb, Kb, Vb);
  k_attn<<<400, 256, 0, stream>>>(Qb, Kb, Vb, ctx);
  k_head<<<100, 256, 0, stream>>>(ctx, out_w, out_b, l1w, l1b, l2w, l2b, out);
}

// Round 9
// 186.930 us; speedup vs baseline: 1.1393x; 1.0700x over previous
//
#include <hip/hip_runtime.h>
#include <math.h>

#define N_N 20000
#define N_E 160000
#define KA 2112   // A cols: 2048 (P) + 32 (xsum for b2) + 32 (x*cnt for root_w)
#define NKB 66

typedef __attribute__((ext_vector_type(8))) short bfrag;
typedef __attribute__((ext_vector_type(4))) float facc;

__device__ __forceinline__ unsigned short f2bf(float f) {
  union { float f; unsigned u; } v; v.f = f;
  unsigned u = v.u;
  return (unsigned short)((u + 0x7FFF + ((u >> 16) & 1)) >> 16);
}
__device__ __forceinline__ unsigned pk2(float a, float b) {
  return (unsigned)f2bf(a) | ((unsigned)f2bf(b) << 16);
}
__device__ __forceinline__ float bflo(unsigned u) {
  union { unsigned u; float f; } v; v.u = u << 16; return v.f;
}
__device__ __forceinline__ float bfhi(unsigned u) {
  union { unsigned u; float f; } v; v.u = u & 0xffff0000u; return v.f;
}

// ---------------- edge MLP layer 1 -> bf16 he, written PERMUTED to dst-sorted order ------
__global__ __launch_bounds__(256) void k_mlp1(const float* __restrict__ ea,
    const float* __restrict__ w1, const float* __restrict__ b1,
    const int* __restrict__ perm, unsigned short* __restrict__ hes) {
  int t = threadIdx.x, w = t >> 6, j = t & 63;
  int e0 = (blockIdx.x * 4 + w) * 8;
  float wr[16];
#pragma unroll
  for (int i = 0; i < 16; ++i) wr[i] = w1[j * 16 + i];
  float bj = b1[j];
#pragma unroll
  for (int q = 0; q < 8; ++q) {
    int e = e0 + q;
    const float* a = ea + (size_t)e * 16;
    float s = bj;
#pragma unroll
    for (int i = 0; i < 16; ++i) s += a[i] * wr[i];
    hes[(size_t)perm[e] * 64 + j] = f2bf(fmaxf(s, 0.f));
  }
}

// ---------------- CSR build by dst ----------------
__global__ __launch_bounds__(256) void k_hist(const int* __restrict__ eidx,
    int* __restrict__ cnt) {
  int e = blockIdx.x * 256 + threadIdx.x;
  atomicAdd(&cnt[eidx[N_E + e]], 1);
}

__global__ __launch_bounds__(1024) void k_scan(int* __restrict__ hist,
    int* __restrict__ starts) {
  __shared__ int part[1024];
  int t = threadIdx.x;
  const int CH = 20;
  int lo = t * CH;
  int hi = lo + CH; if (hi > N_N) hi = N_N;
  int s = 0;
  for (int i = lo; i < hi; ++i) s += hist[i];
  part[t] = s;
  __syncthreads();
  for (int off = 1; off < 1024; off <<= 1) {
    int v = (t >= off) ? part[t - off] : 0;
    __syncthreads();
    part[t] += v;
    __syncthreads();
  }
  int run = (t == 0) ? 0 : part[t - 1];
  for (int i = lo; i < hi; ++i) {
    int h = hist[i];
    starts[i] = run;
    hist[i] = run;          // cursor seed
    run += h;
  }
  if (t == 1023) starts[N_N] = part[1023];
}

__global__ __launch_bounds__(256) void k_scatter(const int* __restrict__ eidx,
    int* __restrict__ cur, int* __restrict__ perm, int* __restrict__ srcl) {
  int e = blockIdx.x * 256 + threadIdx.x;
  int dn = eidx[N_E + e];
  int pos = atomicAdd(&cur[dn], 1);
  perm[e] = pos;
  srcl[pos] = eidx[e];
}

// ---------------- pack B (gemm), B2 (qkv) fragment layouts ----------------
__global__ __launch_bounds__(256) void k_pack(const float* __restrict__ w2,
    const float* __restrict__ b2f, const float* __restrict__ rootw,
    const float* __restrict__ inw,
    unsigned short* __restrict__ Bp, unsigned short* __restrict__ B2p) {
  int idx = blockIdx.x * 256 + threadIdx.x;
  if (idx < 135168) {
    int i = idx & 7, l = (idx >> 3) & 63, cbkb = idx >> 9;
    int cb = cbkb & 3, kb = cbkb >> 2;
    int r = kb * 32 + ((l >> 4) << 3) + i;
    int c = (cb << 4) + (l & 15);
    float v;
    if (r < 2048) { int d = r >> 6, k = r & 63; v = w2[((d << 6) + c) * 64 + k]; }
    else if (r < 2080) v = b2f[((r - 2048) << 6) + c];
    else v = rootw[((r - 2080) << 6) + c];
    Bp[idx] = f2bf(v);
  } else if (idx < 135168 + 12288) {
    int k2 = idx - 135168;
    int i = k2 & 7, l = (k2 >> 3) & 63, cbkb = k2 >> 9;
    int cb = cbkb % 12, kb = cbkb / 12;
    int r = kb * 32 + ((l >> 4) << 3) + i;
    int c = (cb << 4) + (l & 15);
    B2p[k2] = f2bf(inw[c * 64 + r]);
  }
}

// ---------------- FUSED: P-build (LDS) + MFMA GEMM (M=8) + mean/bias/relu + QKV ----------
// Block = 8 nodes, wave = 2 nodes. P in LDS, chunk c of row m stored at chunk c^m.
// Lane l owns d {l>>3, +8, +16, +24} x k (l&7)*8..+8; chunks {l, l+64, l+128, l+192}.
#define FMA8(hv, base, xv) \
  acc[base + 0] += xv * bflo(hv.x); acc[base + 1] += xv * bfhi(hv.x); \
  acc[base + 2] += xv * bflo(hv.y); acc[base + 3] += xv * bfhi(hv.y); \
  acc[base + 4] += xv * bflo(hv.z); acc[base + 5] += xv * bfhi(hv.z); \
  acc[base + 6] += xv * bflo(hv.w); acc[base + 7] += xv * bfhi(hv.w);

__global__ __launch_bounds__(256, 4) void k_fused(const float* __restrict__ x,
    const unsigned short* __restrict__ hes, const int* __restrict__ starts,
    const int* __restrict__ srcl,
    const unsigned short* __restrict__ Bp, const unsigned short* __restrict__ B2p,
    const float* __restrict__ convb, const float* __restrict__ inb,
    float* __restrict__ Qb, float* __restrict__ Kb, float* __restrict__ Vb) {
  __shared__ unsigned short Ps[8 * KA];      // 33,792 B
  __shared__ unsigned short xhT[8 * 68];     //  1,088 B
  int t = threadIdx.x, w = t >> 6, l = t & 63;
  int n0 = blockIdx.x * 8;
  int d0 = l >> 3, hc = (l & 7) * 8;
  // ---- phase 1: each wave builds 2 node rows of P (R5-proven loop) ----
#pragma unroll 1
  for (int i4 = 0; i4 < 2; ++i4) {
    int m = w * 2 + i4;
    int n = n0 + m;
    int s0 = starts[n], s1 = starts[n + 1];
    float acc[32];
#pragma unroll
    for (int z = 0; z < 32; ++z) acc[z] = 0.f;
    float xs = 0.f;
    int i = s0;
#pragma unroll 1
    for (; i + 1 < s1; i += 2) {
      int sr0 = srcl[i], sr1 = srcl[i + 1];
      uint4 h0 = *(const uint4*)(hes + (size_t)i * 64 + hc);
      uint4 h1 = *(const uint4*)(hes + (size_t)(i + 1) * 64 + hc);
      const float* xr0 = x + sr0 * 32;
      const float* xr1 = x + sr1 * 32;
      float a0 = xr0[d0], a1 = xr0[d0 + 8], a2 = xr0[d0 + 16], a3 = xr0[d0 + 24];
      float b0 = xr1[d0], b1 = xr1[d0 + 8], b2 = xr1[d0 + 16], b3 = xr1[d0 + 24];
      FMA8(h0, 0, a0) FMA8(h0, 8, a1) FMA8(h0, 16, a2) FMA8(h0, 24, a3)
      FMA8(h1, 0, b0) FMA8(h1, 8, b1) FMA8(h1, 16, b2) FMA8(h1, 24, b3)
      if (l < 32) xs += xr0[l] + xr1[l];
    }
    if (i < s1) {
      int sr0 = srcl[i];
      uint4 h0 = *(const uint4*)(hes + (size_t)i * 64 + hc);
      const float* xr0 = x + sr0 * 32;
      float a0 = xr0[d0], a1 = xr0[d0 + 8], a2 = xr0[d0 + 16], a3 = xr0[d0 + 24];
      FMA8(h0, 0, a0) FMA8(h0, 8, a1) FMA8(h0, 16, a2) FMA8(h0, 24, a3)
      if (l < 32) xs += xr0[l];
    }
    int s = m;   // m in 0..7
#pragma unroll
    for (int q = 0; q < 4; ++q) {
      int sc = (l + 64 * q) ^ s;
      uint4 o;
      o.x = pk2(acc[q * 8 + 0], acc[q * 8 + 1]);
      o.y = pk2(acc[q * 8 + 2], acc[q * 8 + 3]);
      o.z = pk2(acc[q * 8 + 4], acc[q * 8 + 5]);
      o.w = pk2(acc[q * 8 + 6], acc[q * 8 + 7]);
      *(uint4*)(Ps + m * KA + sc * 8) = o;
    }
    if (l < 32) {
      int cnt = s1 - s0; if (cnt < 1) cnt = 1;
      int c1 = (256 + (l >> 3)) ^ s, c2 = (260 + (l >> 3)) ^ s;
      Ps[m * KA + c1 * 8 + (l & 7)] = f2bf(xs);
      Ps[m * KA + c2 * 8 + (l & 7)] = f2bf(x[n * 32 + l] * (float)cnt);
    }
  }
  __syncthreads();
  // ---- phase 2: GEMM K-loop (M=8, rows duplicated), wave w owns cols w*16..+16 ----
  int col = l & 15, sub = l >> 4;
  int arow = col & 7;
  const bfrag* Bb = (const bfrag*)Bp + w * 64 + l;
  facc ac = {0.f, 0.f, 0.f, 0.f};
#pragma unroll 4
  for (int kb = 0; kb < NKB; ++kb) {
    int sc = ((kb << 2) + sub) ^ arow;
    bfrag af = *(const bfrag*)(Ps + arow * KA + sc * 8);
    ac = __builtin_amdgcn_mfma_f32_16x16x32_bf16(af, Bb[kb * 256], ac, 0, 0, 0);
  }
  float cv = convb[w * 16 + col];
#pragma unroll
  for (int j = 0; j < 4; ++j) {
    int m = sub * 4 + j;
    if (m < 8) {
      int n = n0 + m;
      int cnt = starts[n + 1] - starts[n]; if (cnt < 1) cnt = 1;
      float inv = 1.f / (float)cnt;
      xhT[m * 68 + w * 16 + col] = f2bf(fmaxf(ac[j] * inv + cv, 0.f));
    }
  }
  __syncthreads();
  // ---- phase 3: QKV (M=8), wave w owns 3 of 12 col blocks ----
  bfrag af0 = *(const bfrag*)&xhT[(col & 7) * 68 + sub * 8];
  bfrag af1 = *(const bfrag*)&xhT[(col & 7) * 68 + 32 + sub * 8];
  const bfrag* B2b = (const bfrag*)B2p + l;
#pragma unroll
  for (int c3 = 0; c3 < 3; ++c3) {
    int cb = w * 3 + c3;
    facc qa = {0.f, 0.f, 0.f, 0.f};
    qa = __builtin_amdgcn_mfma_f32_16x16x32_bf16(af0, B2b[cb * 64], qa, 0, 0, 0);
    qa = __builtin_amdgcn_mfma_f32_16x16x32_bf16(af1, B2b[(12 + cb) * 64], qa, 0, 0, 0);
#pragma unroll
    for (int j = 0; j < 4; ++j) {
      int m = sub * 4 + j;
      if (m < 8) {
        int n = n0 + m;
        int g = n / 200, p = n - g * 200;
        int c = cb * 16 + col;
        float v = qa[j] + inb[c];
        int part = c >> 6, rem = c & 63, hh = rem >> 4, dd = rem & 15;
        float* dst = (part == 0) ? Qb : (part == 1 ? Kb : Vb);
        dst[(((size_t)g * 4 + hh) * 200 + p) * 16 + dd] = v;
      }
    }
  }
}

// ---------------- MFMA flash attention: two blocks per (graph, head) ----------------
__global__ __launch_bounds__(256) void k_attn(const float* __restrict__ Qb,
    const float* __restrict__ Kb, const float* __restrict__ Vb,
    float* __restrict__ ctx) {
  __shared__ unsigned short Ks[224 * 24];
  __shared__ unsigned short Vt[16 * 232];
  __shared__ unsigned short Pl[4][16 * 40];
  int t = threadIdx.x;
  int gh = blockIdx.x >> 1, half = blockIdx.x & 1;
  size_t base = (size_t)gh * 3200;
  for (int idx = t; idx < 224 * 16; idx += 256) {
    int row = idx >> 4, d = idx & 15;
    float kv = (row < 200) ? Kb[base + idx] : 0.f;
    float vv = (row < 200) ? Vb[base + idx] : 0.f;
    Ks[row * 24 + d] = f2bf(kv);
    Vt[d * 232 + row] = f2bf(vv);
  }
  __syncthreads();
  int w = t >> 6, l = t & 63;
  int sub = l >> 4, col = l & 15;
  int qlo = half * 7, qhi = half ? 13 : 7;
  for (int qt = qlo + w; qt < qhi; qt += 4) {
    bfrag qf = {0, 0, 0, 0, 0, 0, 0, 0};
    int q = qt * 16 + col;
    if (sub < 2 && q < 200) {
      const float* qp = Qb + base + q * 16 + sub * 8;
      float4 qa = *(const float4*)qp;
      float4 qb = *(const float4*)(qp + 4);
      qf[0] = (short)f2bf(qa.x); qf[1] = (short)f2bf(qa.y);
      qf[2] = (short)f2bf(qa.z); qf[3] = (short)f2bf(qa.w);
      qf[4] = (short)f2bf(qb.x); qf[5] = (short)f2bf(qb.y);
      qf[6] = (short)f2bf(qb.z); qf[7] = (short)f2bf(qb.w);
    }
    facc o = {0.f, 0.f, 0.f, 0.f};
    float srow0 = 0.f, srow1 = 0.f, srow2 = 0.f, srow3 = 0.f;
    for (int kt2 = 0; kt2 < 7; ++kt2) {
      int kt0 = kt2 * 2, kt1 = kt0 + 1;
      bfrag kf0 = {0, 0, 0, 0, 0, 0, 0, 0};
      bfrag kf1 = {0, 0, 0, 0, 0, 0, 0, 0};
      if (sub < 2) {
        kf0 = *(const bfrag*)&Ks[(kt0 * 16 + col) * 24 + sub * 8];
        kf1 = *(const bfrag*)&Ks[(kt1 * 16 + col) * 24 + sub * 8];
      }
      facc z = {0.f, 0.f, 0.f, 0.f};
      facc s0 = __builtin_amdgcn_mfma_f32_16x16x32_bf16(qf, kf0, z, 0, 0, 0);
      facc s1 = __builtin_amdgcn_mfma_f32_16x16x32_bf16(qf, kf1, z, 0, 0, 0);
      bool ok0 = (kt0 * 16 + col) < 200;
      bool ok1 = (kt1 * 16 + col) < 200;
#pragma unroll
      for (int j = 0; j < 4; ++j) {
        float e0 = ok0 ? __expf(s0[j] * 0.25f) : 0.f;
        float e1 = ok1 ? __expf(s1[j] * 0.25f) : 0.f;
        if (j == 0) { srow0 += e0 + e1; } else if (j == 1) { srow1 += e0 + e1; }
        else if (j == 2) { srow2 += e0 + e1; } else { srow3 += e0 + e1; }
        int qr = (sub << 2) + j;
        Pl[w][qr * 40 + col] = f2bf(e0);
        Pl[w][qr * 40 + 16 + col] = f2bf(e1);
      }
      bfrag pf = *(const bfrag*)&Pl[w][col * 40 + sub * 8];
      bfrag vf = *(const bfrag*)&Vt[col * 232 + kt2 * 32 + sub * 8];
      o = __builtin_amdgcn_mfma_f32_16x16x32_bf16(pf, vf, o, 0, 0, 0);
    }
#pragma unroll
    for (int off = 1; off < 16; off <<= 1) {
      srow0 += __shfl_xor(srow0, off);
      srow1 += __shfl_xor(srow1, off);
      srow2 += __shfl_xor(srow2, off);
      srow3 += __shfl_xor(srow3, off);
    }
#pragma unroll
    for (int j = 0; j < 4; ++j) {
      int qq = qt * 16 + (sub << 2) + j;
      float sr = (j == 0) ? srow0 : (j == 1) ? srow1 : (j == 2) ? srow2 : srow3;
      if (qq < 200) ctx[base + qq * 16 + col] = o[j] / sr;
    }
  }
}

// ---------------- pool + MLP head (256 threads: 4-way split pool) ----------------
__global__ __launch_bounds__(256) void k_head(const float* __restrict__ ctx,
    const float* __restrict__ ow, const float* __restrict__ ob,
    const float* __restrict__ w1, const float* __restrict__ b1,
    const float* __restrict__ w2, const float* __restrict__ b2,
    float* __restrict__ out) {
  __shared__ float pool[4][64];
  __shared__ float ms[64], es[64];
  int g = blockIdx.x, t = threadIdx.x;
  int q = t >> 6, c = t & 63;
  int hh = c >> 4, dd = c & 15;
  const float* cb = ctx + (((size_t)g * 4 + hh) * 200) * 16 + dd;
  float s = 0.f;
  for (int p = q; p < 200; p += 4) s += cb[p * 16];
  pool[q][c] = s;
  __syncthreads();
  if (t < 64) {
    float sm = pool[0][t] + pool[1][t] + pool[2][t] + pool[3][t];
    ms[t] = sm * (1.f / 200.f);
  }
  __syncthreads();
  if (t < 64) {
    float e = ob[t];
    for (int j = 0; j < 64; ++j) e += ow[t * 64 + j] * ms[j];
    es[t] = e;
  }
  __syncthreads();
  if (t < 64) {
    float h1 = b1[t];
    for (int j = 0; j < 64; ++j) h1 += w1[t * 64 + j] * es[j];
    h1 = fmaxf(h1, 0.f);
    float pr = h1 * w2[t];
    for (int off = 32; off >= 1; off >>= 1) pr += __shfl_xor(pr, off);
    if (t == 0) out[g] = pr + b2[0];
  }
}

extern "C" void kernel_launch(void* const* d_in, const int* in_sizes, int n_in,
                              void* d_out, int out_size, void* d_ws, size_t ws_size,
                              hipStream_t stream) {
  (void)in_sizes; (void)n_in;
  const float* x      = (const float*)d_in[0];
  const int*   eidx   = (const int*)d_in[1];
  const float* ea     = (const float*)d_in[2];
  const float* en_w1  = (const float*)d_in[4];
  const float* en_b1  = (const float*)d_in[5];
  const float* en_w2  = (const float*)d_in[6];
  const float* en_b2  = (const float*)d_in[7];
  const float* root_w = (const float*)d_in[8];
  const float* conv_b = (const float*)d_in[9];
  const float* in_w   = (const float*)d_in[10];
  const float* in_b   = (const float*)d_in[11];
  const float* out_w  = (const float*)d_in[12];
  const float* out_b  = (const float*)d_in[13];
  const float* l1w    = (const float*)d_in[14];
  const float* l1b    = (const float*)d_in[15];
  const float* l2w    = (const float*)d_in[16];
  const float* l2b    = (const float*)d_in[17];
  float* out = (float*)d_out;

  // ---- workspace layout (bytes) ----
  char* w = (char*)d_ws;
  unsigned short* hes = (unsigned short*)w;            // 20,480,000 (dst-sorted he)
  float* Qb  = (float*)(w + 20480000);
  float* Kb  = (float*)(w + 25600000);
  float* Vb  = (float*)(w + 30720000);
  float* ctx = (float*)(w + 35840000);                 // ends 40,960,000
  char* r3 = w + 40960000;
  unsigned short* Bp  = (unsigned short*)r3;             // 270,336
  unsigned short* B2p = (unsigned short*)(r3 + 270336);  // 24,576
  int* starts = (int*)(r3 + 270336 + 24576);
  int* perm   = starts + (N_N + 4);
  int* srcl   = perm + N_E;
  int* cursor = srcl + N_E;
  size_t need = 40960000 + 270336 + 24576
              + (size_t)(N_N + 4) * 4 + 2 * (size_t)N_E * 4 + (size_t)N_N * 4;
  if (ws_size < need || out_size < 100) return;

  hipMemsetAsync(cursor, 0, N_N * 4, stream);
  k_pack<<<580, 256, 0, stream>>>(en_w2, en_b2, root_w, in_w, Bp, B2p);
  k_hist<<<N_E / 256, 256, 0, stream>>>(eidx, cursor);
  k_scan<<<1, 1024, 0, stream>>>(cursor, starts);
  k_scatter<<<N_E / 256, 256, 0, stream>>>(eidx, cursor, perm, srcl);
  k_mlp1<<<5000, 256, 0, stream>>>(ea, en_w1, en_b1, perm, hes);
  k_fused<<<2500, 256, 0, stream>>>(x, hes, starts, srcl, Bp, B2p,
                                    conv_b, in_b, Qb, Kb, Vb);
  k_attn<<<800, 256, 0, stream>>>(Qb, Kb, Vb, ctx);
  k_head<<<100, 256, 0, stream>>>(ctx, out_w, out_b, l1w, l1b, l2w, l2b, out);
}

// Round 10
// 186.680 us; speedup vs baseline: 1.1408x; 1.0013x over previous
//
#include <hip/hip_runtime.h>
#include <math.h>

#define N_N 20000
#define N_E 160000
#define KA 2112   // A cols: 2048 (P) + 32 (xsum for b2) + 32 (x*cnt for root_w)
#define NKB 66

typedef __attribute__((ext_vector_type(8))) short bfrag;
typedef __attribute__((ext_vector_type(4))) float facc;

__device__ __forceinline__ unsigned short f2bf(float f) {
  union { float f; unsigned u; } v; v.f = f;
  unsigned u = v.u;
  return (unsigned short)((u + 0x7FFF + ((u >> 16) & 1)) >> 16);
}
__device__ __forceinline__ unsigned pk2(float a, float b) {
  return (unsigned)f2bf(a) | ((unsigned)f2bf(b) << 16);
}
__device__ __forceinline__ float bflo(unsigned u) {
  union { unsigned u; float f; } v; v.u = u << 16; return v.f;
}
__device__ __forceinline__ float bfhi(unsigned u) {
  union { unsigned u; float f; } v; v.u = u & 0xffff0000u; return v.f;
}

// ---------------- edge MLP layer 1, slot-ordered (gather reads, coalesced writes) --------
__global__ __launch_bounds__(256) void k_mlp1(const float* __restrict__ ea,
    const float* __restrict__ w1, const float* __restrict__ b1,
    const int* __restrict__ elist, unsigned short* __restrict__ hes) {
  int t = threadIdx.x, w = t >> 6, j = t & 63;
  int p0 = blockIdx.x * 32 + w * 8;
  float wr[16];
#pragma unroll
  for (int i = 0; i < 16; ++i) wr[i] = w1[j * 16 + i];
  float bj = b1[j];
#pragma unroll
  for (int q = 0; q < 8; ++q) {
    int p = p0 + q;
    int e = elist[p];
    const float* a = ea + (size_t)e * 16;
    float s = bj;
#pragma unroll
    for (int i = 0; i < 16; ++i) s += a[i] * wr[i];
    hes[(size_t)p * 64 + j] = f2bf(fmaxf(s, 0.f));
  }
}

// ---------------- CSR build by dst ----------------
__global__ __launch_bounds__(256) void k_hist(const int* __restrict__ eidx,
    int* __restrict__ cnt) {
  int e = blockIdx.x * 256 + threadIdx.x;
  atomicAdd(&cnt[eidx[N_E + e]], 1);
}

__global__ __launch_bounds__(1024) void k_scan(int* __restrict__ hist,
    int* __restrict__ starts) {
  __shared__ int part[1024];
  int t = threadIdx.x;
  const int CH = 20;
  int lo = t * CH;
  int hi = lo + CH; if (hi > N_N) hi = N_N;
  int s = 0;
  for (int i = lo; i < hi; ++i) s += hist[i];
  part[t] = s;
  __syncthreads();
  for (int off = 1; off < 1024; off <<= 1) {
    int v = (t >= off) ? part[t - off] : 0;
    __syncthreads();
    part[t] += v;
    __syncthreads();
  }
  int run = (t == 0) ? 0 : part[t - 1];
  for (int i = lo; i < hi; ++i) {
    int h = hist[i];
    starts[i] = run;
    hist[i] = run;          // cursor seed
    run += h;
  }
  if (t == 1023) starts[N_N] = part[1023];
}

__global__ __launch_bounds__(256) void k_scatter(const int* __restrict__ eidx,
    int* __restrict__ cur, int* __restrict__ elist, int* __restrict__ srcl) {
  int e = blockIdx.x * 256 + threadIdx.x;
  int dn = eidx[N_E + e];
  int pos = atomicAdd(&cur[dn], 1);
  elist[pos] = e;
  srcl[pos] = eidx[e];
}

// ---------------- pack B (gemm), B2 (qkv) fragment layouts ----------------
__global__ __launch_bounds__(256) void k_pack(const float* __restrict__ w2,
    const float* __restrict__ b2f, const float* __restrict__ rootw,
    const float* __restrict__ inw,
    unsigned short* __restrict__ Bp, unsigned short* __restrict__ B2p) {
  int idx = blockIdx.x * 256 + threadIdx.x;
  if (idx < 135168) {
    int i = idx & 7, l = (idx >> 3) & 63, cbkb = idx >> 9;
    int cb = cbkb & 3, kb = cbkb >> 2;
    int r = kb * 32 + ((l >> 4) << 3) + i;
    int c = (cb << 4) + (l & 15);
    float v;
    if (r < 2048) { int d = r >> 6, k = r & 63; v = w2[((d << 6) + c) * 64 + k]; }
    else if (r < 2080) v = b2f[((r - 2048) << 6) + c];
    else v = rootw[((r - 2080) << 6) + c];
    Bp[idx] = f2bf(v);
  } else if (idx < 135168 + 12288) {
    int k2 = idx - 135168;
    int i = k2 & 7, l = (k2 >> 3) & 63, cbkb = k2 >> 9;
    int cb = cbkb % 12, kb = cbkb / 12;
    int r = kb * 32 + ((l >> 4) << 3) + i;
    int c = (cb << 4) + (l & 15);
    B2p[k2] = f2bf(inw[c * 64 + r]);
  }
}

// ---------------- FUSED: P-build (LDS) + MFMA GEMM (M=8) + mean/bias/relu + QKV ----------
// Block = 8 nodes, wave = 2 nodes. P in LDS, chunk c of row m stored at chunk c^m.
// x distributed via one wave-load + shfl (no per-lane gather).
#define FMA8(hv, base, xv) \
  acc[base + 0] += xv * bflo(hv.x); acc[base + 1] += xv * bfhi(hv.x); \
  acc[base + 2] += xv * bflo(hv.y); acc[base + 3] += xv * bfhi(hv.y); \
  acc[base + 4] += xv * bflo(hv.z); acc[base + 5] += xv * bfhi(hv.z); \
  acc[base + 6] += xv * bflo(hv.w); acc[base + 7] += xv * bfhi(hv.w);

__global__ __launch_bounds__(256, 4) void k_fused(const float* __restrict__ x,
    const unsigned short* __restrict__ hes, const int* __restrict__ starts,
    const int* __restrict__ srcl,
    const unsigned short* __restrict__ Bp, const unsigned short* __restrict__ B2p,
    const float* __restrict__ convb, const float* __restrict__ inb,
    float* __restrict__ Qb, float* __restrict__ Kb, float* __restrict__ Vb) {
  __shared__ unsigned short Ps[8 * KA];      // 33,792 B
  __shared__ unsigned short xhT[8 * 68];     //  1,088 B
  int t = threadIdx.x, w = t >> 6, l = t & 63;
  int n0 = blockIdx.x * 8;
  int d0 = l >> 3, hc = (l & 7) * 8, l31 = l & 31;
  // ---- phase 1: each wave builds 2 node rows of P ----
#pragma unroll 1
  for (int i4 = 0; i4 < 2; ++i4) {
    int m = w * 2 + i4;
    int n = n0 + m;
    int s0 = starts[n], s1 = starts[n + 1];
    float acc[32];
#pragma unroll
    for (int z = 0; z < 32; ++z) acc[z] = 0.f;
    float xs = 0.f;
    int i = s0;
#pragma unroll 1
    for (; i + 1 < s1; i += 2) {
      int sr0 = srcl[i], sr1 = srcl[i + 1];
      uint4 h0 = *(const uint4*)(hes + (size_t)i * 64 + hc);
      uint4 h1 = *(const uint4*)(hes + (size_t)(i + 1) * 64 + hc);
      float xv0 = x[(size_t)sr0 * 32 + l31];
      float xv1 = x[(size_t)sr1 * 32 + l31];
      float a0 = __shfl(xv0, d0),      a1 = __shfl(xv0, d0 + 8);
      float a2 = __shfl(xv0, d0 + 16), a3 = __shfl(xv0, d0 + 24);
      float b0 = __shfl(xv1, d0),      b1 = __shfl(xv1, d0 + 8);
      float b2 = __shfl(xv1, d0 + 16), b3 = __shfl(xv1, d0 + 24);
      FMA8(h0, 0, a0) FMA8(h0, 8, a1) FMA8(h0, 16, a2) FMA8(h0, 24, a3)
      FMA8(h1, 0, b0) FMA8(h1, 8, b1) FMA8(h1, 16, b2) FMA8(h1, 24, b3)
      if (l < 32) xs += xv0 + xv1;
    }
    if (i < s1) {
      int sr0 = srcl[i];
      uint4 h0 = *(const uint4*)(hes + (size_t)i * 64 + hc);
      float xv0 = x[(size_t)sr0 * 32 + l31];
      float a0 = __shfl(xv0, d0),      a1 = __shfl(xv0, d0 + 8);
      float a2 = __shfl(xv0, d0 + 16), a3 = __shfl(xv0, d0 + 24);
      FMA8(h0, 0, a0) FMA8(h0, 8, a1) FMA8(h0, 16, a2) FMA8(h0, 24, a3)
      if (l < 32) xs += xv0;
    }
    int s = m;   // m in 0..7
#pragma unroll
    for (int q = 0; q < 4; ++q) {
      int sc = (l + 64 * q) ^ s;
      uint4 o;
      o.x = pk2(acc[q * 8 + 0], acc[q * 8 + 1]);
      o.y = pk2(acc[q * 8 + 2], acc[q * 8 + 3]);
      o.z = pk2(acc[q * 8 + 4], acc[q * 8 + 5]);
      o.w = pk2(acc[q * 8 + 6], acc[q * 8 + 7]);
      *(uint4*)(Ps + m * KA + sc * 8) = o;
    }
    if (l < 32) {
      int cnt = s1 - s0; if (cnt < 1) cnt = 1;
      int c1 = (256 + (l >> 3)) ^ s, c2 = (260 + (l >> 3)) ^ s;
      Ps[m * KA + c1 * 8 + (l & 7)] = f2bf(xs);
      Ps[m * KA + c2 * 8 + (l & 7)] = f2bf(x[(size_t)n * 32 + l] * (float)cnt);
    }
  }
  __syncthreads();
  // ---- phase 2: GEMM K-loop (M=8, rows duplicated), wave w owns cols w*16..+16 ----
  int col = l & 15, sub = l >> 4;
  int arow = col & 7;
  const bfrag* Bb = (const bfrag*)Bp + w * 64 + l;
  facc ac = {0.f, 0.f, 0.f, 0.f};
#pragma unroll 4
  for (int kb = 0; kb < NKB; ++kb) {
    int sc = ((kb << 2) + sub) ^ arow;
    bfrag af = *(const bfrag*)(Ps + arow * KA + sc * 8);
    ac = __builtin_amdgcn_mfma_f32_16x16x32_bf16(af, Bb[kb * 256], ac, 0, 0, 0);
  }
  float cv = convb[w * 16 + col];
#pragma unroll
  for (int j = 0; j < 4; ++j) {
    int m = sub * 4 + j;
    if (m < 8) {
      int n = n0 + m;
      int cnt = starts[n + 1] - starts[n]; if (cnt < 1) cnt = 1;
      float inv = 1.f / (float)cnt;
      xhT[m * 68 + w * 16 + col] = f2bf(fmaxf(ac[j] * inv + cv, 0.f));
    }
  }
  __syncthreads();
  // ---- phase 3: QKV (M=8), wave w owns 3 of 12 col blocks ----
  bfrag af0 = *(const bfrag*)&xhT[(col & 7) * 68 + sub * 8];
  bfrag af1 = *(const bfrag*)&xhT[(col & 7) * 68 + 32 + sub * 8];
  const bfrag* B2b = (const bfrag*)B2p + l;
#pragma unroll
  for (int c3 = 0; c3 < 3; ++c3) {
    int cb = w * 3 + c3;
    facc qa = {0.f, 0.f, 0.f, 0.f};
    qa = __builtin_amdgcn_mfma_f32_16x16x32_bf16(af0, B2b[cb * 64], qa, 0, 0, 0);
    qa = __builtin_amdgcn_mfma_f32_16x16x32_bf16(af1, B2b[(12 + cb) * 64], qa, 0, 0, 0);
#pragma unroll
    for (int j = 0; j < 4; ++j) {
      int m = sub * 4 + j;
      if (m < 8) {
        int n = n0 + m;
        int g = n / 200, p = n - g * 200;
        int c = cb * 16 + col;
        float v = qa[j] + inb[c];
        int part = c >> 6, rem = c & 63, hh = rem >> 4, dd = rem & 15;
        float* dst = (part == 0) ? Qb : (part == 1 ? Kb : Vb);
        dst[(((size_t)g * 4 + hh) * 200 + p) * 16 + dd] = v;
      }
    }
  }
}

// ---------------- MFMA flash attention: two blocks per (graph, head) ----------------
__global__ __launch_bounds__(256) void k_attn(const float* __restrict__ Qb,
    const float* __restrict__ Kb, const float* __restrict__ Vb,
    float* __restrict__ ctx) {
  __shared__ unsigned short Ks[224 * 24];
  __shared__ unsigned short Vt[16 * 232];
  __shared__ unsigned short Pl[4][16 * 40];
  int t = threadIdx.x;
  int gh = blockIdx.x >> 1, half = blockIdx.x & 1;
  size_t base = (size_t)gh * 3200;
  for (int idx = t; idx < 224 * 16; idx += 256) {
    int row = idx >> 4, d = idx & 15;
    float kv = (row < 200) ? Kb[base + idx] : 0.f;
    float vv = (row < 200) ? Vb[base + idx] : 0.f;
    Ks[row * 24 + d] = f2bf(kv);
    Vt[d * 232 + row] = f2bf(vv);
  }
  __syncthreads();
  int w = t >> 6, l = t & 63;
  int sub = l >> 4, col = l & 15;
  int qlo = half * 7, qhi = half ? 13 : 7;
  for (int qt = qlo + w; qt < qhi; qt += 4) {
    bfrag qf = {0, 0, 0, 0, 0, 0, 0, 0};
    int q = qt * 16 + col;
    if (sub < 2 && q < 200) {
      const float* qp = Qb + base + q * 16 + sub * 8;
      float4 qa = *(const float4*)qp;
      float4 qb = *(const float4*)(qp + 4);
      qf[0] = (short)f2bf(qa.x); qf[1] = (short)f2bf(qa.y);
      qf[2] = (short)f2bf(qa.z); qf[3] = (short)f2bf(qa.w);
      qf[4] = (short)f2bf(qb.x); qf[5] = (short)f2bf(qb.y);
      qf[6] = (short)f2bf(qb.z); qf[7] = (short)f2bf(qb.w);
    }
    facc o = {0.f, 0.f, 0.f, 0.f};
    float srow0 = 0.f, srow1 = 0.f, srow2 = 0.f, srow3 = 0.f;
    for (int kt2 = 0; kt2 < 7; ++kt2) {
      int kt0 = kt2 * 2, kt1 = kt0 + 1;
      bfrag kf0 = {0, 0, 0, 0, 0, 0, 0, 0};
      bfrag kf1 = {0, 0, 0, 0, 0, 0, 0, 0};
      if (sub < 2) {
        kf0 = *(const bfrag*)&Ks[(kt0 * 16 + col) * 24 + sub * 8];
        kf1 = *(const bfrag*)&Ks[(kt1 * 16 + col) * 24 + sub * 8];
      }
      facc z = {0.f, 0.f, 0.f, 0.f};
      facc s0 = __builtin_amdgcn_mfma_f32_16x16x32_bf16(qf, kf0, z, 0, 0, 0);
      facc s1 = __builtin_amdgcn_mfma_f32_16x16x32_bf16(qf, kf1, z, 0, 0, 0);
      bool ok0 = (kt0 * 16 + col) < 200;
      bool ok1 = (kt1 * 16 + col) < 200;
#pragma unroll
      for (int j = 0; j < 4; ++j) {
        float e0 = ok0 ? __expf(s0[j] * 0.25f) : 0.f;
        float e1 = ok1 ? __expf(s1[j] * 0.25f) : 0.f;
        if (j == 0) { srow0 += e0 + e1; } else if (j == 1) { srow1 += e0 + e1; }
        else if (j == 2) { srow2 += e0 + e1; } else { srow3 += e0 + e1; }
        int qr = (sub << 2) + j;
        Pl[w][qr * 40 + col] = f2bf(e0);
        Pl[w][qr * 40 + 16 + col] = f2bf(e1);
      }
      bfrag pf = *(const bfrag*)&Pl[w][col * 40 + sub * 8];
      bfrag vf = *(const bfrag*)&Vt[col * 232 + kt2 * 32 + sub * 8];
      o = __builtin_amdgcn_mfma_f32_16x16x32_bf16(pf, vf, o, 0, 0, 0);
    }
#pragma unroll
    for (int off = 1; off < 16; off <<= 1) {
      srow0 += __shfl_xor(srow0, off);
      srow1 += __shfl_xor(srow1, off);
      srow2 += __shfl_xor(srow2, off);
      srow3 += __shfl_xor(srow3, off);
    }
#pragma unroll
    for (int j = 0; j < 4; ++j) {
      int qq = qt * 16 + (sub << 2) + j;
      float sr = (j == 0) ? srow0 : (j == 1) ? srow1 : (j == 2) ? srow2 : srow3;
      if (qq < 200) ctx[base + qq * 16 + col] = o[j] / sr;
    }
  }
}

// ---------------- pool + MLP head (256 threads: 4-way split pool) ----------------
__global__ __launch_bounds__(256) void k_head(const float* __restrict__ ctx,
    const float* __restrict__ ow, const float* __restrict__ ob,
    const float* __restrict__ w1, const float* __restrict__ b1,
    const float* __restrict__ w2, const float* __restrict__ b2,
    float* __restrict__ out) {
  __shared__ float pool[4][64];
  __shared__ float ms[64], es[64];
  int g = blockIdx.x, t = threadIdx.x;
  int q = t >> 6, c = t & 63;
  int hh = c >> 4, dd = c & 15;
  const float* cb = ctx + (((size_t)g * 4 + hh) * 200) * 16 + dd;
  float s = 0.f;
  for (int p = q; p < 200; p += 4) s += cb[p * 16];
  pool[q][c] = s;
  __syncthreads();
  if (t < 64) {
    float sm = pool[0][t] + pool[1][t] + pool[2][t] + pool[3][t];
    ms[t] = sm * (1.f / 200.f);
  }
  __syncthreads();
  if (t < 64) {
    float e = ob[t];
    for (int j = 0; j < 64; ++j) e += ow[t * 64 + j] * ms[j];
    es[t] = e;
  }
  __syncthreads();
  if (t < 64) {
    float h1 = b1[t];
    for (int j = 0; j < 64; ++j) h1 += w1[t * 64 + j] * es[j];
    h1 = fmaxf(h1, 0.f);
    float pr = h1 * w2[t];
    for (int off = 32; off >= 1; off >>= 1) pr += __shfl_xor(pr, off);
    if (t == 0) out[g] = pr + b2[0];
  }
}

extern "C" void kernel_launch(void* const* d_in, const int* in_sizes, int n_in,
                              void* d_out, int out_size, void* d_ws, size_t ws_size,
                              hipStream_t stream) {
  (void)in_sizes; (void)n_in;
  const float* x      = (const float*)d_in[0];
  const int*   eidx   = (const int*)d_in[1];
  const float* ea     = (const float*)d_in[2];
  const float* en_w1  = (const float*)d_in[4];
  const float* en_b1  = (const float*)d_in[5];
  const float* en_w2  = (const float*)d_in[6];
  const float* en_b2  = (const float*)d_in[7];
  const float* root_w = (const float*)d_in[8];
  const float* conv_b = (const float*)d_in[9];
  const float* in_w   = (const float*)d_in[10];
  const float* in_b   = (const float*)d_in[11];
  const float* out_w  = (const float*)d_in[12];
  const float* out_b  = (const float*)d_in[13];
  const float* l1w    = (const float*)d_in[14];
  const float* l1b    = (const float*)d_in[15];
  const float* l2w    = (const float*)d_in[16];
  const float* l2b    = (const float*)d_in[17];
  float* out = (float*)d_out;

  // ---- workspace layout (bytes) ----
  char* w = (char*)d_ws;
  unsigned short* hes = (unsigned short*)w;            // 20,480,000 (dst-sorted he)
  float* Qb  = (float*)(w + 20480000);
  float* Kb  = (float*)(w + 25600000);
  float* Vb  = (float*)(w + 30720000);
  float* ctx = (float*)(w + 35840000);                 // ends 40,960,000
  char* r3 = w + 40960000;
  unsigned short* Bp  = (unsigned short*)r3;             // 270,336
  unsigned short* B2p = (unsigned short*)(r3 + 270336);  // 24,576
  int* starts = (int*)(r3 + 270336 + 24576);
  int* elist  = starts + (N_N + 4);
  int* srcl   = elist + N_E;
  int* cursor = srcl + N_E;
  size_t need = 40960000 + 270336 + 24576
              + (size_t)(N_N + 4) * 4 + 2 * (size_t)N_E * 4 + (size_t)N_N * 4;
  if (ws_size < need || out_size < 100) return;

  hipMemsetAsync(cursor, 0, N_N * 4, stream);
  k_pack<<<580, 256, 0, stream>>>(en_w2, en_b2, root_w, in_w, Bp, B2p);
  k_hist<<<N_E / 256, 256, 0, stream>>>(eidx, cursor);
  k_scan<<<1, 1024, 0, stream>>>(cursor, starts);
  k_scatter<<<N_E / 256, 256, 0, stream>>>(eidx, cursor, elist, srcl);
  k_mlp1<<<5000, 256, 0, stream>>>(ea, en_w1, en_b1, elist, hes);
  k_fused<<<2500, 256, 0, stream>>>(x, hes, starts, srcl, Bp, B2p,
                                    conv_b, in_b, Qb, Kb, Vb);
  k_attn<<<800, 256, 0, stream>>>(Qb, Kb, Vb, ctx);
  k_head<<<100, 256, 0, stream>>>(ctx, out_w, out_b, l1w, l1b, l2w, l2b, out);
}

// Round 11
// 180.682 us; speedup vs baseline: 1.1787x; 1.0332x over previous
//
#include <hip/hip_runtime.h>
#include <math.h>

#define N_N 20000
#define N_E 160000
#define KA 2112   // A cols: 2048 (P) + 32 (xsum for b2) + 32 (x*cnt for root_w)
#define NKB 66

typedef __attribute__((ext_vector_type(8))) short bfrag;
typedef __attribute__((ext_vector_type(4))) float facc;

__device__ __forceinline__ unsigned short f2bf(float f) {
  union { float f; unsigned u; } v; v.f = f;
  unsigned u = v.u;
  return (unsigned short)((u + 0x7FFF + ((u >> 16) & 1)) >> 16);
}
__device__ __forceinline__ unsigned pk2(float a, float b) {
  return (unsigned)f2bf(a) | ((unsigned)f2bf(b) << 16);
}
__device__ __forceinline__ float bflo(unsigned u) {
  union { unsigned u; float f; } v; v.u = u << 16; return v.f;
}
__device__ __forceinline__ float bfhi(unsigned u) {
  union { unsigned u; float f; } v; v.u = u & 0xffff0000u; return v.f;
}

// ---------------- edge MLP layer 1, slot-ordered (gather reads, coalesced writes) --------
__global__ __launch_bounds__(256) void k_mlp1(const float* __restrict__ ea,
    const float* __restrict__ w1, const float* __restrict__ b1,
    const int* __restrict__ elist, unsigned short* __restrict__ hes) {
  int t = threadIdx.x, w = t >> 6, j = t & 63;
  int p0 = blockIdx.x * 32 + w * 8;
  float wr[16];
#pragma unroll
  for (int i = 0; i < 16; ++i) wr[i] = w1[j * 16 + i];
  float bj = b1[j];
#pragma unroll
  for (int q = 0; q < 8; ++q) {
    int p = p0 + q;
    int e = elist[p];
    const float* a = ea + (size_t)e * 16;
    float s = bj;
#pragma unroll
    for (int i = 0; i < 16; ++i) s += a[i] * wr[i];
    hes[(size_t)p * 64 + j] = f2bf(fmaxf(s, 0.f));
  }
}

// ---------------- CSR build by dst ----------------
__global__ __launch_bounds__(256) void k_hist(const int* __restrict__ eidx,
    int* __restrict__ cnt) {
  int e = blockIdx.x * 256 + threadIdx.x;
  atomicAdd(&cnt[eidx[N_E + e]], 1);
}

__global__ __launch_bounds__(1024) void k_scan(int* __restrict__ hist,
    int* __restrict__ starts) {
  __shared__ int part[1024];
  int t = threadIdx.x;
  const int CH = 20;
  int lo = t * CH;
  int hi = lo + CH; if (hi > N_N) hi = N_N;
  int s = 0;
  for (int i = lo; i < hi; ++i) s += hist[i];
  part[t] = s;
  __syncthreads();
  for (int off = 1; off < 1024; off <<= 1) {
    int v = (t >= off) ? part[t - off] : 0;
    __syncthreads();
    part[t] += v;
    __syncthreads();
  }
  int run = (t == 0) ? 0 : part[t - 1];
  for (int i = lo; i < hi; ++i) {
    int h = hist[i];
    starts[i] = run;
    hist[i] = run;          // cursor seed
    run += h;
  }
  if (t == 1023) starts[N_N] = part[1023];
}

__global__ __launch_bounds__(256) void k_scatter(const int* __restrict__ eidx,
    int* __restrict__ cur, int* __restrict__ elist, int* __restrict__ srcl) {
  int e = blockIdx.x * 256 + threadIdx.x;
  int dn = eidx[N_E + e];
  int pos = atomicAdd(&cur[dn], 1);
  elist[pos] = e;
  srcl[pos] = eidx[e];
}

// ---------------- pack B (gemm), B2 (qkv) fragment layouts ----------------
__global__ __launch_bounds__(256) void k_pack(const float* __restrict__ w2,
    const float* __restrict__ b2f, const float* __restrict__ rootw,
    const float* __restrict__ inw,
    unsigned short* __restrict__ Bp, unsigned short* __restrict__ B2p) {
  int idx = blockIdx.x * 256 + threadIdx.x;
  if (idx < 135168) {
    int i = idx & 7, l = (idx >> 3) & 63, cbkb = idx >> 9;
    int cb = cbkb & 3, kb = cbkb >> 2;
    int r = kb * 32 + ((l >> 4) << 3) + i;
    int c = (cb << 4) + (l & 15);
    float v;
    if (r < 2048) { int d = r >> 6, k = r & 63; v = w2[((d << 6) + c) * 64 + k]; }
    else if (r < 2080) v = b2f[((r - 2048) << 6) + c];
    else v = rootw[((r - 2080) << 6) + c];
    Bp[idx] = f2bf(v);
  } else if (idx < 135168 + 12288) {
    int k2 = idx - 135168;
    int i = k2 & 7, l = (k2 >> 3) & 63, cbkb = k2 >> 9;
    int cb = cbkb % 12, kb = cbkb / 12;
    int r = kb * 32 + ((l >> 4) << 3) + i;
    int c = (cb << 4) + (l & 15);
    B2p[k2] = f2bf(inw[c * 64 + r]);
  }
}

// ---------------- FUSED: P-build (LDS) + MFMA GEMM (M=8) + mean/bias/relu + QKV ----------
// Block = 8 nodes, wave = 2 nodes. P in LDS, chunk c of row m stored at chunk c^m.
// Per 64-edge chunk: srcl preloaded once (lane l holds slot c0+l), distributed by shfl;
// consume loop 4x-unrolled -> 8 independent loads in flight, no load-load dep chain.
#define FMA8(hv, base, xv) \
  acc[base + 0] += xv * bflo(hv.x); acc[base + 1] += xv * bfhi(hv.x); \
  acc[base + 2] += xv * bflo(hv.y); acc[base + 3] += xv * bfhi(hv.y); \
  acc[base + 4] += xv * bflo(hv.z); acc[base + 5] += xv * bfhi(hv.z); \
  acc[base + 6] += xv * bflo(hv.w); acc[base + 7] += xv * bfhi(hv.w);

__global__ __launch_bounds__(256, 4) void k_fused(const float* __restrict__ x,
    const unsigned short* __restrict__ hes, const int* __restrict__ starts,
    const int* __restrict__ srcl,
    const unsigned short* __restrict__ Bp, const unsigned short* __restrict__ B2p,
    const float* __restrict__ convb, const float* __restrict__ inb,
    float* __restrict__ Qb, float* __restrict__ Kb, float* __restrict__ Vb) {
  __shared__ unsigned short Ps[8 * KA];      // 33,792 B
  __shared__ unsigned short xhT[8 * 68];     //  1,088 B
  int t = threadIdx.x, w = t >> 6, l = t & 63;
  int n0 = blockIdx.x * 8;
  int d0 = l >> 3, hc = (l & 7) * 8, l31 = l & 31;
  // ---- phase 1: each wave builds 2 node rows of P ----
#pragma unroll 1
  for (int i4 = 0; i4 < 2; ++i4) {
    int m = w * 2 + i4;
    int n = n0 + m;
    int s0 = starts[n], s1 = starts[n + 1];
    float acc[32];
#pragma unroll
    for (int z = 0; z < 32; ++z) acc[z] = 0.f;
    float xs = 0.f;
#pragma unroll 1
    for (int c0 = s0; c0 < s1; c0 += 64) {
      int srv = 0;
      if (c0 + l < s1) srv = srcl[c0 + l];
      int cc = s1 - c0; if (cc > 64) cc = 64;
#pragma unroll 1
      for (int i = 0; i < cc; i += 4) {
        uint4 h0 = {0,0,0,0}, h1 = {0,0,0,0}, h2 = {0,0,0,0}, h3 = {0,0,0,0};
        float xv0 = 0.f, xv1 = 0.f, xv2 = 0.f, xv3 = 0.f;
        int sr0 = __shfl(srv, i);
        int sr1 = __shfl(srv, i + 1);
        int sr2 = __shfl(srv, i + 2);
        int sr3 = __shfl(srv, i + 3);
        const unsigned short* hp = hes + (size_t)(c0 + i) * 64 + hc;
        h0 = *(const uint4*)hp;
        xv0 = x[(size_t)sr0 * 32 + l31];
        if (i + 1 < cc) { h1 = *(const uint4*)(hp + 64);  xv1 = x[(size_t)sr1 * 32 + l31]; }
        if (i + 2 < cc) { h2 = *(const uint4*)(hp + 128); xv2 = x[(size_t)sr2 * 32 + l31]; }
        if (i + 3 < cc) { h3 = *(const uint4*)(hp + 192); xv3 = x[(size_t)sr3 * 32 + l31]; }
        float a0 = __shfl(xv0, d0),      a1 = __shfl(xv0, d0 + 8);
        float a2 = __shfl(xv0, d0 + 16), a3 = __shfl(xv0, d0 + 24);
        FMA8(h0, 0, a0) FMA8(h0, 8, a1) FMA8(h0, 16, a2) FMA8(h0, 24, a3)
        float b0 = __shfl(xv1, d0),      b1 = __shfl(xv1, d0 + 8);
        float b2 = __shfl(xv1, d0 + 16), b3 = __shfl(xv1, d0 + 24);
        FMA8(h1, 0, b0) FMA8(h1, 8, b1) FMA8(h1, 16, b2) FMA8(h1, 24, b3)
        float c0f = __shfl(xv2, d0),      c1f = __shfl(xv2, d0 + 8);
        float c2f = __shfl(xv2, d0 + 16), c3f = __shfl(xv2, d0 + 24);
        FMA8(h2, 0, c0f) FMA8(h2, 8, c1f) FMA8(h2, 16, c2f) FMA8(h2, 24, c3f)
        float e0 = __shfl(xv3, d0),      e1 = __shfl(xv3, d0 + 8);
        float e2 = __shfl(xv3, d0 + 16), e3 = __shfl(xv3, d0 + 24);
        FMA8(h3, 0, e0) FMA8(h3, 8, e1) FMA8(h3, 16, e2) FMA8(h3, 24, e3)
        xs += xv0 + xv1 + xv2 + xv3;
      }
    }
    int s = m;   // m in 0..7
#pragma unroll
    for (int q = 0; q < 4; ++q) {
      int sc = (l + 64 * q) ^ s;
      uint4 o;
      o.x = pk2(acc[q * 8 + 0], acc[q * 8 + 1]);
      o.y = pk2(acc[q * 8 + 2], acc[q * 8 + 3]);
      o.z = pk2(acc[q * 8 + 4], acc[q * 8 + 5]);
      o.w = pk2(acc[q * 8 + 6], acc[q * 8 + 7]);
      *(uint4*)(Ps + m * KA + sc * 8) = o;
    }
    if (l < 32) {
      int cnt = s1 - s0; if (cnt < 1) cnt = 1;
      int c1 = (256 + (l >> 3)) ^ s, c2 = (260 + (l >> 3)) ^ s;
      Ps[m * KA + c1 * 8 + (l & 7)] = f2bf(xs);
      Ps[m * KA + c2 * 8 + (l & 7)] = f2bf(x[(size_t)n * 32 + l] * (float)cnt);
    }
  }
  __syncthreads();
  // ---- phase 2: GEMM K-loop (M=8, rows duplicated), wave w owns cols w*16..+16 ----
  int col = l & 15, sub = l >> 4;
  int arow = col & 7;
  const bfrag* Bb = (const bfrag*)Bp + w * 64 + l;
  facc ac = {0.f, 0.f, 0.f, 0.f};
#pragma unroll 4
  for (int kb = 0; kb < NKB; ++kb) {
    int sc = ((kb << 2) + sub) ^ arow;
    bfrag af = *(const bfrag*)(Ps + arow * KA + sc * 8);
    ac = __builtin_amdgcn_mfma_f32_16x16x32_bf16(af, Bb[kb * 256], ac, 0, 0, 0);
  }
  float cv = convb[w * 16 + col];
#pragma unroll
  for (int j = 0; j < 4; ++j) {
    int m = sub * 4 + j;
    if (m < 8) {
      int n = n0 + m;
      int cnt = starts[n + 1] - starts[n]; if (cnt < 1) cnt = 1;
      float inv = 1.f / (float)cnt;
      xhT[m * 68 + w * 16 + col] = f2bf(fmaxf(ac[j] * inv + cv, 0.f));
    }
  }
  __syncthreads();
  // ---- phase 3: QKV (M=8), wave w owns 3 of 12 col blocks ----
  bfrag af0 = *(const bfrag*)&xhT[(col & 7) * 68 + sub * 8];
  bfrag af1 = *(const bfrag*)&xhT[(col & 7) * 68 + 32 + sub * 8];
  const bfrag* B2b = (const bfrag*)B2p + l;
#pragma unroll
  for (int c3 = 0; c3 < 3; ++c3) {
    int cb = w * 3 + c3;
    facc qa = {0.f, 0.f, 0.f, 0.f};
    qa = __builtin_amdgcn_mfma_f32_16x16x32_bf16(af0, B2b[cb * 64], qa, 0, 0, 0);
    qa = __builtin_amdgcn_mfma_f32_16x16x32_bf16(af1, B2b[(12 + cb) * 64], qa, 0, 0, 0);
#pragma unroll
    for (int j = 0; j < 4; ++j) {
      int m = sub * 4 + j;
      if (m < 8) {
        int n = n0 + m;
        int g = n / 200, p = n - g * 200;
        int c = cb * 16 + col;
        float v = qa[j] + inb[c];
        int part = c >> 6, rem = c & 63, hh = rem >> 4, dd = rem & 15;
        float* dst = (part == 0) ? Qb : (part == 1 ? Kb : Vb);
        dst[(((size_t)g * 4 + hh) * 200 + p) * 16 + dd] = v;
      }
    }
  }
}

// ---------------- MFMA flash attention: two blocks per (graph, head) ----------------
__global__ __launch_bounds__(256) void k_attn(const float* __restrict__ Qb,
    const float* __restrict__ Kb, const float* __restrict__ Vb,
    float* __restrict__ ctx) {
  __shared__ unsigned short Ks[224 * 24];
  __shared__ unsigned short Vt[16 * 232];
  __shared__ unsigned short Pl[4][16 * 40];
  int t = threadIdx.x;
  int gh = blockIdx.x >> 1, half = blockIdx.x & 1;
  size_t base = (size_t)gh * 3200;
  for (int idx = t; idx < 224 * 16; idx += 256) {
    int row = idx >> 4, d = idx & 15;
    float kv = (row < 200) ? Kb[base + idx] : 0.f;
    float vv = (row < 200) ? Vb[base + idx] : 0.f;
    Ks[row * 24 + d] = f2bf(kv);
    Vt[d * 232 + row] = f2bf(vv);
  }
  __syncthreads();
  int w = t >> 6, l = t & 63;
  int sub = l >> 4, col = l & 15;
  int qlo = half * 7, qhi = half ? 13 : 7;
  for (int qt = qlo + w; qt < qhi; qt += 4) {
    bfrag qf = {0, 0, 0, 0, 0, 0, 0, 0};
    int q = qt * 16 + col;
    if (sub < 2 && q < 200) {
      const float* qp = Qb + base + q * 16 + sub * 8;
      float4 qa = *(const float4*)qp;
      float4 qb = *(const float4*)(qp + 4);
      qf[0] = (short)f2bf(qa.x); qf[1] = (short)f2bf(qa.y);
      qf[2] = (short)f2bf(qa.z); qf[3] = (short)f2bf(qa.w);
      qf[4] = (short)f2bf(qb.x); qf[5] = (short)f2bf(qb.y);
      qf[6] = (short)f2bf(qb.z); qf[7] = (short)f2bf(qb.w);
    }
    facc o = {0.f, 0.f, 0.f, 0.f};
    float srow0 = 0.f, srow1 = 0.f, srow2 = 0.f, srow3 = 0.f;
    for (int kt2 = 0; kt2 < 7; ++kt2) {
      int kt0 = kt2 * 2, kt1 = kt0 + 1;
      bfrag kf0 = {0, 0, 0, 0, 0, 0, 0, 0};
      bfrag kf1 = {0, 0, 0, 0, 0, 0, 0, 0};
      if (sub < 2) {
        kf0 = *(const bfrag*)&Ks[(kt0 * 16 + col) * 24 + sub * 8];
        kf1 = *(const bfrag*)&Ks[(kt1 * 16 + col) * 24 + sub * 8];
      }
      facc z = {0.f, 0.f, 0.f, 0.f};
      facc s0 = __builtin_amdgcn_mfma_f32_16x16x32_bf16(qf, kf0, z, 0, 0, 0);
      facc s1 = __builtin_amdgcn_mfma_f32_16x16x32_bf16(qf, kf1, z, 0, 0, 0);
      bool ok0 = (kt0 * 16 + col) < 200;
      bool ok1 = (kt1 * 16 + col) < 200;
#pragma unroll
      for (int j = 0; j < 4; ++j) {
        float e0 = ok0 ? __expf(s0[j] * 0.25f) : 0.f;
        float e1 = ok1 ? __expf(s1[j] * 0.25f) : 0.f;
        if (j == 0) { srow0 += e0 + e1; } else if (j == 1) { srow1 += e0 + e1; }
        else if (j == 2) { srow2 += e0 + e1; } else { srow3 += e0 + e1; }
        int qr = (sub << 2) + j;
        Pl[w][qr * 40 + col] = f2bf(e0);
        Pl[w][qr * 40 + 16 + col] = f2bf(e1);
      }
      bfrag pf = *(const bfrag*)&Pl[w][col * 40 + sub * 8];
      bfrag vf = *(const bfrag*)&Vt[col * 232 + kt2 * 32 + sub * 8];
      o = __builtin_amdgcn_mfma_f32_16x16x32_bf16(pf, vf, o, 0, 0, 0);
    }
#pragma unroll
    for (int off = 1; off < 16; off <<= 1) {
      srow0 += __shfl_xor(srow0, off);
      srow1 += __shfl_xor(srow1, off);
      srow2 += __shfl_xor(srow2, off);
      srow3 += __shfl_xor(srow3, off);
    }
#pragma unroll
    for (int j = 0; j < 4; ++j) {
      int qq = qt * 16 + (sub << 2) + j;
      float sr = (j == 0) ? srow0 : (j == 1) ? srow1 : (j == 2) ? srow2 : srow3;
      if (qq < 200) ctx[base + qq * 16 + col] = o[j] / sr;
    }
  }
}

// ---------------- pool + MLP head (256 threads: 4-way split pool) ----------------
__global__ __launch_bounds__(256) void k_head(const float* __restrict__ ctx,
    const float* __restrict__ ow, const float* __restrict__ ob,
    const float* __restrict__ w1, const float* __restrict__ b1,
    const float* __restrict__ w2, const float* __restrict__ b2,
    float* __restrict__ out) {
  __shared__ float pool[4][64];
  __shared__ float ms[64], es[64];
  int g = blockIdx.x, t = threadIdx.x;
  int q = t >> 6, c = t & 63;
  int hh = c >> 4, dd = c & 15;
  const float* cb = ctx + (((size_t)g * 4 + hh) * 200) * 16 + dd;
  float s = 0.f;
  for (int p = q; p < 200; p += 4) s += cb[p * 16];
  pool[q][c] = s;
  __syncthreads();
  if (t < 64) {
    float sm = pool[0][t] + pool[1][t] + pool[2][t] + pool[3][t];
    ms[t] = sm * (1.f / 200.f);
  }
  __syncthreads();
  if (t < 64) {
    float e = ob[t];
    for (int j = 0; j < 64; ++j) e += ow[t * 64 + j] * ms[j];
    es[t] = e;
  }
  __syncthreads();
  if (t < 64) {
    float h1 = b1[t];
    for (int j = 0; j < 64; ++j) h1 += w1[t * 64 + j] * es[j];
    h1 = fmaxf(h1, 0.f);
    float pr = h1 * w2[t];
    for (int off = 32; off >= 1; off >>= 1) pr += __shfl_xor(pr, off);
    if (t == 0) out[g] = pr + b2[0];
  }
}

extern "C" void kernel_launch(void* const* d_in, const int* in_sizes, int n_in,
                              void* d_out, int out_size, void* d_ws, size_t ws_size,
                              hipStream_t stream) {
  (void)in_sizes; (void)n_in;
  const float* x      = (const float*)d_in[0];
  const int*   eidx   = (const int*)d_in[1];
  const float* ea     = (const float*)d_in[2];
  const float* en_w1  = (const float*)d_in[4];
  const float* en_b1  = (const float*)d_in[5];
  const float* en_w2  = (const float*)d_in[6];
  const float* en_b2  = (const float*)d_in[7];
  const float* root_w = (const float*)d_in[8];
  const float* conv_b = (const float*)d_in[9];
  const float* in_w   = (const float*)d_in[10];
  const float* in_b   = (const float*)d_in[11];
  const float* out_w  = (const float*)d_in[12];
  const float* out_b  = (const float*)d_in[13];
  const float* l1w    = (const float*)d_in[14];
  const float* l1b    = (const float*)d_in[15];
  const float* l2w    = (const float*)d_in[16];
  const float* l2b    = (const float*)d_in[17];
  float* out = (float*)d_out;

  // ---- workspace layout (bytes) ----
  char* w = (char*)d_ws;
  unsigned short* hes = (unsigned short*)w;            // 20,480,000 (dst-sorted he)
  float* Qb  = (float*)(w + 20480000);
  float* Kb  = (float*)(w + 25600000);
  float* Vb  = (float*)(w + 30720000);
  float* ctx = (float*)(w + 35840000);                 // ends 40,960,000
  char* r3 = w + 40960000;
  unsigned short* Bp  = (unsigned short*)r3;             // 270,336
  unsigned short* B2p = (unsigned short*)(r3 + 270336);  // 24,576
  int* starts = (int*)(r3 + 270336 + 24576);
  int* elist  = starts + (N_N + 4);
  int* srcl   = elist + N_E;
  int* cursor = srcl + N_E;
  size_t need = 40960000 + 270336 + 24576
              + (size_t)(N_N + 4) * 4 + 2 * (size_t)N_E * 4 + (size_t)N_N * 4;
  if (ws_size < need || out_size < 100) return;

  hipMemsetAsync(cursor, 0, N_N * 4, stream);
  k_pack<<<580, 256, 0, stream>>>(en_w2, en_b2, root_w, in_w, Bp, B2p);
  k_hist<<<N_E / 256, 256, 0, stream>>>(eidx, cursor);
  k_scan<<<1, 1024, 0, stream>>>(cursor, starts);
  k_scatter<<<N_E / 256, 256, 0, stream>>>(eidx, cursor, elist, srcl);
  k_mlp1<<<5000, 256, 0, stream>>>(ea, en_w1, en_b1, elist, hes);
  k_fused<<<2500, 256, 0, stream>>>(x, hes, starts, srcl, Bp, B2p,
                                    conv_b, in_b, Qb, Kb, Vb);
  k_attn<<<800, 256, 0, stream>>>(Qb, Kb, Vb, ctx);
  k_head<<<100, 256, 0, stream>>>(ctx, out_w, out_b, l1w, l1b, l2w, l2b, out);
}